// Round 4
// baseline (928.886 us; speedup 1.0000x reference)
//
#include <hip/hip_runtime.h>
#include <hip/hip_bf16.h>
#include <math.h>

// Round 4: flash attention with precomputed hi/lo bf16 K and V^T (conversion
// hoisted out of the O(T^2) loop), no-LDS direct-from-L2 fragment loads,
// XCD-aware block swizzle. GEMMs unchanged.
// B=2 T=2048 D=1024 NH=16 HD=64 HALF=32 NEXP=8 TOPK=2 CAP=1024 FF=4096

#define TT 2048
#define NTOK 4096

typedef __attribute__((ext_vector_type(8))) short bf16x8;
typedef __attribute__((ext_vector_type(4))) float f32x4;

static __device__ __forceinline__ ushort f2bf(float f) {
  union { float f; unsigned u; } v; v.f = f;
  unsigned r = v.u + 0x7FFFu + ((v.u >> 16) & 1u);
  return (ushort)(r >> 16);
}
static __device__ __forceinline__ float bf2f(ushort h) {
  union { unsigned u; float f; } v; v.u = ((unsigned)h) << 16; return v.f;
}

// ---------------------------------------------------------------- LayerNorm
__global__ __launch_bounds__(256)
void ln_kernel(const float* __restrict__ x, const float* __restrict__ g,
               const float* __restrict__ b, float* __restrict__ out) {
  int row = blockIdx.x, tid = threadIdx.x;
  const float4* xr = (const float4*)(x + (size_t)row * 1024);
  float4 v = xr[tid];
  float s = v.x + v.y + v.z + v.w;
  #pragma unroll
  for (int off = 1; off < 64; off <<= 1) s += __shfl_xor(s, off);
  __shared__ float red1[4], red2[4];
  if ((tid & 63) == 0) red1[tid >> 6] = s;
  __syncthreads();
  float mu = (red1[0] + red1[1] + red1[2] + red1[3]) * (1.0f / 1024.0f);
  float dx = v.x - mu, dy = v.y - mu, dz = v.z - mu, dw = v.w - mu;
  float ss = dx*dx + dy*dy + dz*dz + dw*dw;
  #pragma unroll
  for (int off = 1; off < 64; off <<= 1) ss += __shfl_xor(ss, off);
  if ((tid & 63) == 0) red2[tid >> 6] = ss;
  __syncthreads();
  float var = (red2[0] + red2[1] + red2[2] + red2[3]) * (1.0f / 1024.0f);
  float inv = 1.0f / sqrtf(var + 1e-5f);
  float4 g4 = ((const float4*)g)[tid];
  float4 b4 = ((const float4*)b)[tid];
  float4 o4;
  o4.x = dx * inv * g4.x + b4.x;
  o4.y = dy * inv * g4.y + b4.y;
  o4.z = dz * inv * g4.z + b4.z;
  o4.w = dw * inv * g4.w + b4.w;
  ((float4*)(out + (size_t)row * 1024))[tid] = o4;
}

// ---------------------------------------------------------------- RoPE tables (f64)
__global__ void sincos_kernel(float* __restrict__ st, float* __restrict__ ct) {
  int t = blockIdx.x, j = threadIdx.x;
  double invf = pow(10000.0, -((double)(2 * j)) / 64.0);
  double ang = (double)t * invf;
  st[t * 32 + j] = (float)sin(ang);
  ct[t * 32 + j] = (float)cos(ang);
}

// ---------------------------------------------------------------- RoPE apply + k,v outputs + Kh/Kl prep
__global__ __launch_bounds__(256)
void rope_kernel(float* __restrict__ qkv, const float* __restrict__ st,
                 const float* __restrict__ ct, float* __restrict__ kout,
                 float* __restrict__ vout, ushort* __restrict__ Kh,
                 ushort* __restrict__ Kl) {
  int row = blockIdx.x;
  int t = row & (TT - 1);
  int b = row >> 11;
  int tid = threadIdx.x;
  float* base = qkv + (size_t)row * 3072;
  #pragma unroll
  for (int l = 0; l < 2; ++l) {
    int idx = l * 256 + tid;
    int h = idx >> 5, j = idx & 31;
    float s = st[t * 32 + j], c = ct[t * 32 + j];
    float* qp = base + h * 192;
    float q1 = qp[j], q2 = qp[j + 32];
    qp[j]      = q1 * c - q2 * s;
    qp[j + 32] = q1 * s + q2 * c;
    float k1 = qp[64 + j], k2 = qp[96 + j];
    float kr1 = k1 * c - k2 * s, kr2 = k1 * s + k2 * c;
    qp[64 + j] = kr1; qp[96 + j] = kr2;
    kout[(size_t)row * 1024 + h * 64 + j]      = kr1;
    kout[(size_t)row * 1024 + h * 64 + 32 + j] = kr2;
    size_t kb = ((size_t)(b * 16 + h) * TT + t) * 64;
    ushort h1 = f2bf(kr1);
    Kh[kb + j] = h1; Kl[kb + j] = f2bf(kr1 - bf2f(h1));
    ushort h2 = f2bf(kr2);
    Kh[kb + 32 + j] = h2; Kl[kb + 32 + j] = f2bf(kr2 - bf2f(h2));
  }
  #pragma unroll
  for (int l = 0; l < 4; ++l) {
    int f = l * 256 + tid;
    int h = f >> 6, d = f & 63;
    vout[(size_t)row * 1024 + f] = base[h * 192 + 128 + d];
  }
}

// ---------------------------------------------------------------- V^T prep: [b,t,h*64] f32 -> [b,h,64,t] bf16 hi/lo
__global__ __launch_bounds__(256)
void vtprep_kernel(const float* __restrict__ vout, ushort* __restrict__ Vth,
                   ushort* __restrict__ Vtl) {
  __shared__ float tile[64][65];
  int t0 = blockIdx.x * 64, h = blockIdx.y, b = blockIdx.z;
  int tid = threadIdx.x;
  #pragma unroll
  for (int l = 0; l < 4; ++l) {
    int idx = l * 256 + tid;
    int r = idx >> 4, c4 = (idx & 15) * 4;
    *(float4*)&tile[r][c4] = *(const float4*)&vout[((size_t)(b * TT + t0 + r)) * 1024 + h * 64 + c4];
  }
  __syncthreads();
  int d = tid >> 2, ts = (tid & 3) * 16;
  union { bf16x8 v; ushort u[8]; } H0, H1, L0, L1;
  #pragma unroll
  for (int i = 0; i < 8; ++i) {
    float v0 = tile[ts + i][d];
    ushort hb0 = f2bf(v0);
    H0.u[i] = hb0; L0.u[i] = f2bf(v0 - bf2f(hb0));
    float v1 = tile[ts + 8 + i][d];
    ushort hb1 = f2bf(v1);
    H1.u[i] = hb1; L1.u[i] = f2bf(v1 - bf2f(hb1));
  }
  size_t basep = ((size_t)(b * 16 + h) * 64 + d) * TT + t0 + ts;
  *(bf16x8*)(Vth + basep) = H0.v;  *(bf16x8*)(Vth + basep + 8) = H1.v;
  *(bf16x8*)(Vtl + basep) = L0.v;  *(bf16x8*)(Vtl + basep + 8) = L1.v;
}

// ---------------------------------------------------------------- flash attention v4 (MFMA, no LDS)
// grid = 1024 linear blocks; decode XCD-swizzled (4 (b,h) pairs per XCD, qt desc).
// 4 waves x 16 q-rows. S^T = mfma(K, Q^T); PV with in-register P redistribution.
__global__ __launch_bounds__(256)
void flash4_kernel(const float* __restrict__ qkv, const ushort* __restrict__ Kh,
                   const ushort* __restrict__ Kl, const ushort* __restrict__ Vth,
                   const ushort* __restrict__ Vtl, float* __restrict__ o) {
  int lin = blockIdx.x;
  int xcd = lin & 7, slot = lin >> 3;
  int qt = 31 - (slot & 31);
  int pair = (slot >> 5) * 8 + xcd;      // 0..31
  int h = pair & 15, b = pair >> 4;
  int tid = threadIdx.x;
  int w = tid >> 6, lane = tid & 63;
  int lr = lane & 15, lk = lane >> 4;
  size_t bT = (size_t)b * TT;
  int q0 = qt * 64;
  int qg = q0 + w * 16 + lr;
  // Q fragments (B-operand), hi/lo split: d = kst*32 + lk*8 + j
  bf16x8 qh[2], ql[2];
  {
    const float* qp = qkv + (bT + qg) * 3072 + h * 192;
    #pragma unroll
    for (int kst = 0; kst < 2; ++kst) {
      float4 a = *(const float4*)(qp + kst * 32 + lk * 8);
      float4 bq = *(const float4*)(qp + kst * 32 + lk * 8 + 4);
      float vals[8] = {a.x, a.y, a.z, a.w, bq.x, bq.y, bq.z, bq.w};
      union { bf16x8 v; ushort u[8]; } H, L;
      #pragma unroll
      for (int j = 0; j < 8; ++j) {
        ushort hb = f2bf(vals[j]);
        H.u[j] = hb; L.u[j] = f2bf(vals[j] - bf2f(hb));
      }
      qh[kst] = H.v; ql[kst] = L.v;
    }
  }
  const ushort* Kbh = Kh + (size_t)(b * 16 + h) * TT * 64;
  const ushort* Kbl = Kl + (size_t)(b * 16 + h) * TT * 64;
  const ushort* Vbh = Vth + (size_t)(b * 16 + h) * 64 * TT;
  const ushort* Vbl = Vtl + (size_t)(b * 16 + h) * 64 * TT;
  f32x4 accO[4] = {};
  float m = -3.402823466e38f, lsum = 0.0f;

  for (int kt = 0; kt <= qt; ++kt) {
    // ---- K fragments straight from global (L2-resident)
    bf16x8 kfh[2][4], kfl[2][4];
    #pragma unroll
    for (int kst = 0; kst < 2; ++kst)
      #pragma unroll
      for (int mf = 0; mf < 4; ++mf) {
        size_t ad = (size_t)(kt * 64 + mf * 16 + lr) * 64 + kst * 32 + lk * 8;
        kfh[kst][mf] = *(const bf16x8*)(Kbh + ad);
        kfl[kst][mf] = *(const bf16x8*)(Kbl + ad);
      }
    // ---- S^T = K @ Q^T, 3-term split; mf-inner for 4-way MFMA ILP
    f32x4 accS[4] = {};
    #pragma unroll
    for (int kst = 0; kst < 2; ++kst) {
      #pragma unroll
      for (int mf = 0; mf < 4; ++mf)
        accS[mf] = __builtin_amdgcn_mfma_f32_16x16x32_bf16(kfh[kst][mf], qh[kst], accS[mf], 0, 0, 0);
      #pragma unroll
      for (int mf = 0; mf < 4; ++mf)
        accS[mf] = __builtin_amdgcn_mfma_f32_16x16x32_bf16(kfh[kst][mf], ql[kst], accS[mf], 0, 0, 0);
      #pragma unroll
      for (int mf = 0; mf < 4; ++mf)
        accS[mf] = __builtin_amdgcn_mfma_f32_16x16x32_bf16(kfl[kst][mf], qh[kst], accS[mf], 0, 0, 0);
    }
    // ---- scale + (diagonal-only) causal mask + online softmax
    float pmax = -3.402823466e38f;
    if (kt == qt) {
      #pragma unroll
      for (int mf = 0; mf < 4; ++mf)
        #pragma unroll
        for (int r = 0; r < 4; ++r) {
          int kvg = kt * 64 + mf * 16 + lk * 4 + r;
          float sv = (kvg <= qg) ? accS[mf][r] * 0.125f : -3.402823466e38f;
          accS[mf][r] = sv;
          pmax = fmaxf(pmax, sv);
        }
    } else {
      #pragma unroll
      for (int mf = 0; mf < 4; ++mf)
        #pragma unroll
        for (int r = 0; r < 4; ++r) {
          float sv = accS[mf][r] * 0.125f;
          accS[mf][r] = sv;
          pmax = fmaxf(pmax, sv);
        }
    }
    pmax = fmaxf(pmax, __shfl_xor(pmax, 16));
    pmax = fmaxf(pmax, __shfl_xor(pmax, 32));
    float mnew = fmaxf(m, pmax);
    float fsc = __expf(m - mnew);
    float psum = 0.0f;
    #pragma unroll
    for (int mf = 0; mf < 4; ++mf)
      #pragma unroll
      for (int r = 0; r < 4; ++r) {
        float p = __expf(accS[mf][r] - mnew);
        accS[mf][r] = p;
        psum += p;
      }
    psum += __shfl_xor(psum, 16);
    psum += __shfl_xor(psum, 32);
    lsum = lsum * fsc + psum;
    m = mnew;
    // ---- V fragments (issued here; latency hidden under rescale + P assembly)
    bf16x8 vfh[2][4], vfl[2][4];
    #pragma unroll
    for (int kst = 0; kst < 2; ++kst)
      #pragma unroll
      for (int nf = 0; nf < 4; ++nf) {
        size_t ad = (size_t)(nf * 16 + lr) * TT + kt * 64 + kst * 32 + lk * 8;
        vfh[kst][nf] = *(const bf16x8*)(Vbh + ad);
        vfl[kst][nf] = *(const bf16x8*)(Vbl + ad);
      }
    // rescale accO: row q = lk*4+r; factor held at lane lr' = lk*4+r
    #pragma unroll
    for (int r = 0; r < 4; ++r) {
      int srcF = (lane & 48) | (((lane >> 4) & 3) << 2) | r;
      float fr = __shfl(fsc, srcF);
      #pragma unroll
      for (int nf = 0; nf < 4; ++nf) accO[nf][r] *= fr;
    }
    // ---- PV: assemble P A-frags via shfl, 3-term split; nf-inner ILP
    #pragma unroll
    for (int kst = 0; kst < 2; ++kst) {
      float pj[8];
      #pragma unroll
      for (int j = 0; j < 8; ++j) {
        int src = ((((lane & 16) >> 3) + (j >> 2)) << 4) | lr;
        float v0 = __shfl(accS[kst * 2][j & 3], src);
        float v1 = __shfl(accS[kst * 2 + 1][j & 3], src);
        pj[j] = (lane & 32) ? v1 : v0;
      }
      union { bf16x8 v; ushort u[8]; } PH, PL;
      #pragma unroll
      for (int j = 0; j < 8; ++j) {
        ushort hb = f2bf(pj[j]);
        PH.u[j] = hb; PL.u[j] = f2bf(pj[j] - bf2f(hb));
      }
      #pragma unroll
      for (int nf = 0; nf < 4; ++nf)
        accO[nf] = __builtin_amdgcn_mfma_f32_16x16x32_bf16(PH.v, vfh[kst][nf], accO[nf], 0, 0, 0);
      #pragma unroll
      for (int nf = 0; nf < 4; ++nf)
        accO[nf] = __builtin_amdgcn_mfma_f32_16x16x32_bf16(PH.v, vfl[kst][nf], accO[nf], 0, 0, 0);
      #pragma unroll
      for (int nf = 0; nf < 4; ++nf)
        accO[nf] = __builtin_amdgcn_mfma_f32_16x16x32_bf16(PL.v, vfh[kst][nf], accO[nf], 0, 0, 0);
    }
  }
  // ---- epilogue
  #pragma unroll
  for (int r = 0; r < 4; ++r) {
    int srcF = (lane & 48) | (((lane >> 4) & 3) << 2) | r;
    float linv = __shfl(1.0f / lsum, srcF);
    int row = q0 + w * 16 + ((lane >> 4) & 3) * 4 + r;
    #pragma unroll
    for (int nf = 0; nf < 4; ++nf)
      o[(bT + row) * 1024 + h * 64 + nf * 16 + lr] = accO[nf][r] * linv;
  }
}

// ---------------------------------------------------------------- transpose + bf16 convert (+lo split)
template<bool LO>
__global__ void tconv_kernel(const float* __restrict__ in, ushort* __restrict__ oh,
                             ushort* __restrict__ ol, int K, int N) {
  __shared__ float t[32][33];
  int z = blockIdx.z;
  const float* ip = in + (size_t)z * K * N;
  ushort* ohp = oh + (size_t)z * K * N;
  ushort* olp = LO ? (ol + (size_t)z * K * N) : nullptr;
  int n0 = blockIdx.x * 32, k0 = blockIdx.y * 32;
  int tx = threadIdx.x, ty = threadIdx.y;   // (32,8)
  #pragma unroll
  for (int i = 0; i < 4; ++i)
    t[ty + 8 * i][tx] = ip[(size_t)(k0 + ty + 8 * i) * N + n0 + tx];
  __syncthreads();
  #pragma unroll
  for (int i = 0; i < 4; ++i) {
    float v = t[tx][ty + 8 * i];
    size_t off = (size_t)(n0 + ty + 8 * i) * K + k0 + tx;
    ushort hb = f2bf(v);
    ohp[off] = hb;
    if (LO) olp[off] = f2bf(v - bf2f(hb));
  }
}

// ---------------------------------------------------------------- rowwise hi/lo bf16 split
__global__ __launch_bounds__(256)
void split_kernel(const float* __restrict__ in, ushort* __restrict__ oh,
                  ushort* __restrict__ ol) {
  size_t i = ((size_t)blockIdx.x * 256 + threadIdx.x) * 4;
  float4 v = *(const float4*)(in + i);
  ushort h0 = f2bf(v.x), h1 = f2bf(v.y), h2 = f2bf(v.z), h3 = f2bf(v.w);
  ushort4 hh = {h0, h1, h2, h3};
  *(ushort4*)(oh + i) = hh;
  ushort4 ll = {f2bf(v.x - bf2f(h0)), f2bf(v.y - bf2f(h1)),
                f2bf(v.z - bf2f(h2)), f2bf(v.w - bf2f(h3))};
  *(ushort4*)(ol + i) = ll;
}

// ---------------------------------------------------------------- MFMA GEMM
// C[M][N] = A[M][K] @ B^T[N][K]  (bf16 in, fp32 acc). 128x128 tile, 4 waves.
// SPLIT3: logical K' = 3K over segments (Ah,Bh),(Ah,Bl),(Al,Bh).
// EPI: 0 fp32 C; 1 fp32 C+extra; 2 bf16 gelu(C+bias); 3 bf16 C+bias.
#define LOAD_STEP(tt) do {                                                     \
    int seg = SPLIT3 ? ((tt) / kPer) : 0;                                      \
    int kk = (SPLIT3 ? ((tt) % kPer) : (tt)) << 6;                             \
    const ushort* Ause = (SPLIT3 && seg == 2) ? AlB : AhB;                     \
    const ushort* Buse = (SPLIT3 && seg == 1) ? BlB : BhB;                     \
    _Pragma("unroll")                                                          \
    for (int q = 0; q < 4; ++q) {                                              \
      int rr = r0 + 32 * q;                                                    \
      int clog = cph ^ (rr & 7);                                               \
      ra[q] = *(const bf16x8*)(Ause + (size_t)garow[q] * K + kk + clog * 8);   \
      rb[q] = *(const bf16x8*)(Buse + (size_t)(bn + rr) * K + kk + clog * 8);  \
    }                                                                          \
  } while (0)

template<int EPI, bool GATHER, bool SPLIT3>
__global__ __launch_bounds__(256, 2)
void mgemm(const ushort* __restrict__ Ah, const ushort* __restrict__ Al,
           const ushort* __restrict__ Bh, const ushort* __restrict__ Bl,
           void* __restrict__ Cv, const float* __restrict__ extra,
           const int* __restrict__ gatAll, int N, int K,
           long aEStride, long bEStride, long cEStride, int biasEStride) {
  __shared__ ushort As[128 * 64];
  __shared__ ushort Bs[128 * 64];
  int z = blockIdx.z;
  const ushort* AhB = Ah + (size_t)z * aEStride;
  const ushort* AlB = SPLIT3 ? (Al + (size_t)z * aEStride) : nullptr;
  const ushort* BhB = Bh + (size_t)z * bEStride;
  const ushort* BlB = SPLIT3 ? (Bl + (size_t)z * bEStride) : nullptr;
  const int* gat = GATHER ? (gatAll + z * 1024) : nullptr;
  int bm = blockIdx.y * 128, bn = blockIdx.x * 128;
  int tid = threadIdx.x;
  int r0 = tid >> 3, cph = tid & 7;
  int garow[4];
  #pragma unroll
  for (int q = 0; q < 4; ++q) {
    int rr = r0 + 32 * q;
    garow[q] = GATHER ? gat[bm + rr] : (bm + rr);
  }
  int kPer = K >> 6;
  int kSteps = (SPLIT3 ? 3 : 1) * kPer;
  int wid = tid >> 6, lane = tid & 63;
  int wm = wid >> 1, wn = wid & 1;
  int lr = lane & 15, lk = lane >> 4;
  f32x4 acc[4][4] = {};
  bf16x8 ra[4], rb[4];
  LOAD_STEP(0);
  for (int t = 0; t < kSteps; ++t) {
    __syncthreads();
    #pragma unroll
    for (int q = 0; q < 4; ++q) {
      int rr = r0 + 32 * q;
      *(bf16x8*)&As[rr * 64 + cph * 8] = ra[q];
      *(bf16x8*)&Bs[rr * 64 + cph * 8] = rb[q];
    }
    __syncthreads();
    if (t + 1 < kSteps) LOAD_STEP(t + 1);
    #pragma unroll
    for (int kh = 0; kh < 2; ++kh) {
      bf16x8 af[4], bfr[4];
      #pragma unroll
      for (int mf = 0; mf < 4; ++mf) {
        int row = wm * 64 + mf * 16 + lr;
        int ch = (kh * 4 + lk) ^ (row & 7);
        af[mf] = *(const bf16x8*)&As[row * 64 + ch * 8];
      }
      #pragma unroll
      for (int nf = 0; nf < 4; ++nf) {
        int row = wn * 64 + nf * 16 + lr;
        int ch = (kh * 4 + lk) ^ (row & 7);
        bfr[nf] = *(const bf16x8*)&Bs[row * 64 + ch * 8];
      }
      #pragma unroll
      for (int mf = 0; mf < 4; ++mf)
        #pragma unroll
        for (int nf = 0; nf < 4; ++nf)
          acc[mf][nf] = __builtin_amdgcn_mfma_f32_16x16x32_bf16(af[mf], bfr[nf], acc[mf][nf], 0, 0, 0);
    }
  }
  int crow = bm + wm * 64, ccol = bn + wn * 64;
  if constexpr (EPI <= 1) {
    float* C = (float*)Cv;
    #pragma unroll
    for (int mf = 0; mf < 4; ++mf)
      #pragma unroll
      for (int nf = 0; nf < 4; ++nf)
        #pragma unroll
        for (int r = 0; r < 4; ++r) {
          int row = crow + mf * 16 + lk * 4 + r;
          int col = ccol + nf * 16 + lr;
          float v = acc[mf][nf][r];
          if constexpr (EPI == 1) v += extra[(size_t)row * N + col];
          C[(size_t)row * N + col] = v;
        }
  } else {
    const float* bias = extra + (size_t)z * biasEStride;
    ushort* C = (ushort*)Cv + (size_t)z * cEStride;
    #pragma unroll
    for (int mf = 0; mf < 4; ++mf)
      #pragma unroll
      for (int nf = 0; nf < 4; ++nf)
        #pragma unroll
        for (int r = 0; r < 4; ++r) {
          int row = crow + mf * 16 + lk * 4 + r;
          int col = ccol + nf * 16 + lr;
          float v = acc[mf][nf][r] + bias[col];
          if constexpr (EPI == 2)
            v = 0.5f * v * (1.0f + erff(v * 0.70710678118654752f));
          C[(size_t)row * N + col] = f2bf(v);
        }
  }
}

// ---------------------------------------------------------------- gate: softmax + stable top-2
__global__ __launch_bounds__(256)
void gate_kernel(const float* __restrict__ ffin, const float* __restrict__ Wg,
                 int* __restrict__ te, float* __restrict__ tv, int* __restrict__ inv) {
  int token = blockIdx.x, tid = threadIdx.x;
  float acc[8] = {};
  const float* xr = ffin + (size_t)token * 1024;
  for (int i = tid; i < 1024; i += 256) {
    float xv = xr[i];
    const float4* wr = (const float4*)&Wg[i * 8];
    float4 w0 = wr[0], w1 = wr[1];
    acc[0] += xv * w0.x; acc[1] += xv * w0.y; acc[2] += xv * w0.z; acc[3] += xv * w0.w;
    acc[4] += xv * w1.x; acc[5] += xv * w1.y; acc[6] += xv * w1.z; acc[7] += xv * w1.w;
  }
  #pragma unroll
  for (int off = 1; off < 64; off <<= 1)
    #pragma unroll
    for (int q = 0; q < 8; ++q) acc[q] += __shfl_xor(acc[q], off);
  __shared__ float red[4][8];
  if ((tid & 63) == 0)
    #pragma unroll
    for (int q = 0; q < 8; ++q) red[tid >> 6][q] = acc[q];
  __syncthreads();
  if (tid == 0) {
    float g[8];
    #pragma unroll
    for (int q = 0; q < 8; ++q) g[q] = red[0][q] + red[1][q] + red[2][q] + red[3][q];
    float mx = g[0];
    #pragma unroll
    for (int q = 1; q < 8; ++q) mx = fmaxf(mx, g[q]);
    float sum = 0.0f;
    #pragma unroll
    for (int q = 0; q < 8; ++q) { g[q] = expf(g[q] - mx); sum += g[q]; }
    float inv_s = 1.0f / sum;
    #pragma unroll
    for (int q = 0; q < 8; ++q) g[q] *= inv_s;
    int e1 = 0; float v1 = g[0];
    for (int q = 1; q < 8; ++q) if (g[q] > v1) { v1 = g[q]; e1 = q; }
    int e2 = -1; float v2 = -1.0f;
    for (int q = 0; q < 8; ++q) { if (q == e1) continue; if (g[q] > v2) { v2 = g[q]; e2 = q; } }
    te[token * 2] = e1; te[token * 2 + 1] = e2;
    tv[token * 2] = v1; tv[token * 2 + 1] = v2;
    inv[token * 2] = -1; inv[token * 2 + 1] = -1;
  }
}

// ---------------------------------------------------------------- per-expert capacity select
__global__ __launch_bounds__(1024)
void route_sort_kernel(const int* __restrict__ te, const float* __restrict__ tv,
                       int* __restrict__ etok, float* __restrict__ ew,
                       int* __restrict__ inv) {
  __shared__ unsigned long long sk[8192];
  int e = blockIdx.x, tid = threadIdx.x;
  for (int s = tid; s < 8192; s += 1024) {
    unsigned long long key = 0ull;
    if (te[s] == e) {
      unsigned vb = __float_as_uint(tv[s]);
      key = ((unsigned long long)vb << 32) | (unsigned)(0xFFFFFFFFu - (unsigned)s);
    }
    sk[s] = key;
  }
  __syncthreads();
  for (int k = 2; k <= 8192; k <<= 1)
    for (int j = k >> 1; j > 0; j >>= 1) {
      for (int t = tid; t < 4096; t += 1024) {
        int i = ((t & ~(j - 1)) << 1) | (t & (j - 1));
        int p = i | j;
        unsigned long long a = sk[i], bq = sk[p];
        bool desc = ((i & k) == 0);
        bool sw = desc ? (a < bq) : (a > bq);
        if (sw) { sk[i] = bq; sk[p] = a; }
      }
      __syncthreads();
    }
  if (tid < 1024) {
    unsigned long long key = sk[tid];
    bool valid = (key != 0ull);
    unsigned slot = 0xFFFFFFFFu - (unsigned)(key & 0xFFFFFFFFull);
    etok[e * 1024 + tid] = valid ? (int)(slot >> 1) : 0;
    ew[e * 1024 + tid] = valid ? __uint_as_float((unsigned)(key >> 32)) : 0.0f;
    if (valid) inv[slot] = e * 1024 + tid;
  }
}

// ---------------------------------------------------------------- final combine (deterministic)
__global__ __launch_bounds__(256)
void combine_kernel(const float* __restrict__ xres, const ushort* __restrict__ eo,
                    const int* __restrict__ inv, const float* __restrict__ ew,
                    float* __restrict__ outx, float* __restrict__ aux) {
  int token = blockIdx.x;
  int d = threadIdx.x * 4;
  float4 acc = *(const float4*)&xres[(size_t)token * 1024 + d];
  #pragma unroll
  for (int j = 0; j < 2; ++j) {
    int p = inv[token * 2 + j];
    if (p >= 0) {
      float w = ew[p];
      const ushort* ep = eo + (size_t)p * 1024 + d;
      acc.x += w * bf2f(ep[0]); acc.y += w * bf2f(ep[1]);
      acc.z += w * bf2f(ep[2]); acc.w += w * bf2f(ep[3]);
    }
  }
  *(float4*)&outx[(size_t)token * 1024 + d] = acc;
  if (token == 0 && threadIdx.x == 0) aux[0] = 0.0f;
}

// ================================================================ launch
extern "C" void kernel_launch(void* const* d_in, const int* in_sizes, int n_in,
                              void* d_out, int out_size, void* d_ws, size_t ws_size,
                              hipStream_t stream) {
  const float* x     = (const float*)d_in[0];
  const float* ln1g  = (const float*)d_in[1];
  const float* ln1b  = (const float*)d_in[2];
  const float* ln2g  = (const float*)d_in[3];
  const float* ln2b  = (const float*)d_in[4];
  const float* Wqkv  = (const float*)d_in[5];
  const float* Wproj = (const float*)d_in[6];
  const float* Wg    = (const float*)d_in[7];
  const float* W1    = (const float*)d_in[8];
  const float* b1    = (const float*)d_in[9];
  const float* W2    = (const float*)d_in[10];
  const float* b2    = (const float*)d_in[11];

  float* out_x   = (float*)d_out;
  float* out_aux = out_x + 4194304;
  float* out_k   = out_aux + 1;
  float* out_v   = out_k + 4194304;

  float* ws   = (float*)d_ws;
  float* A    = ws;                          // x_norm -> x_res
  float* qkvb = ws + 4194304;                // fp32 qkv (aliased by h later)
  float* o    = ws + 16777216;               // attn out -> ff_in
  float* st   = ws + 20971520;
  float* ct   = ws + 21037056;
  int*   te   = (int*)(ws + 21102592);
  float* tv   = ws + 21110784;
  int*   etok = (int*)(ws + 21118976);
  float* ew   = ws + 21127168;
  int*   inv  = (int*)(ws + 21135360);
  ushort* bfAh = (ushort*)(ws + 21143552);   // [4096][1024] bf16
  ushort* bfAl = (ushort*)(ws + 23240704);
  ushort* BqH  = (ushort*)(ws + 25337856);   // WqkvT hi [3072][1024]
  ushort* BqL  = (ushort*)(ws + 26910720);
  ushort* BpH  = (ushort*)(ws + 28483584);   // WprojT hi [1024][1024]
  ushort* BpL  = (ushort*)(ws + 29007872);
  ushort* W1t  = (ushort*)(ws + 29532160);   // [8][4096][1024]
  ushort* W2t  = (ushort*)(ws + 46309376);   // [8][1024][4096]
  ushort* eo   = (ushort*)(ws + 63086592);   // [8192][1024] bf16
  ushort* hbuf = (ushort*)(ws + 4194304);    // [8][1024][4096] bf16, aliases qkvb+o
  // flash operand buffers (aliased into dead regions during attention):
  ushort* Kh_  = bfAh;                       // [2][16][2048][64]  (bfAh dead after QKV)
  ushort* Kl_  = bfAl;
  ushort* Vth_ = eo;                         // [2][16][64][2048]  (eo dead until experts)
  ushort* Vtl_ = eo + 4194304;

  // weight prep (independent of activations)
  tconv_kernel<true ><<<dim3(96, 32, 1),  dim3(32, 8), 0, stream>>>(Wqkv,  BqH, BqL, 1024, 3072);
  tconv_kernel<true ><<<dim3(32, 32, 1),  dim3(32, 8), 0, stream>>>(Wproj, BpH, BpL, 1024, 1024);
  tconv_kernel<false><<<dim3(128, 32, 8), dim3(32, 8), 0, stream>>>(W1, W1t, nullptr, 1024, 4096);
  tconv_kernel<false><<<dim3(32, 128, 8), dim3(32, 8), 0, stream>>>(W2, W2t, nullptr, 4096, 1024);
  sincos_kernel<<<TT, 32, 0, stream>>>(st, ct);

  // LN1 + split
  ln_kernel<<<NTOK, 256, 0, stream>>>(x, ln1g, ln1b, A);
  split_kernel<<<4096, 256, 0, stream>>>(A, bfAh, bfAl);
  // QKV (split-bf16, K' = 3*1024)
  mgemm<0, false, true><<<dim3(24, 32, 1), 256, 0, stream>>>(
      bfAh, bfAl, BqH, BqL, qkvb, nullptr, nullptr, 3072, 1024, 0, 0, 0, 0);
  // RoPE + k/v outputs + Kh/Kl prep (bfAh/bfAl dead now)
  rope_kernel<<<NTOK, 256, 0, stream>>>(qkvb, st, ct, out_k, out_v, Kh_, Kl_);
  vtprep_kernel<<<dim3(32, 16, 2), 256, 0, stream>>>(out_v, Vth_, Vtl_);
  flash4_kernel<<<1024, 256, 0, stream>>>(qkvb, Kh_, Kl_, Vth_, Vtl_, o);
  // proj + residual (split-bf16; clobbers Kh/Kl — dead)
  split_kernel<<<4096, 256, 0, stream>>>(o, bfAh, bfAl);
  mgemm<1, false, true><<<dim3(8, 32, 1), 256, 0, stream>>>(
      bfAh, bfAl, BpH, BpL, A, x, nullptr, 1024, 1024, 0, 0, 0, 0);
  // LN2 -> ff_in (in o buffer), gate, route
  ln_kernel<<<NTOK, 256, 0, stream>>>(A, ln2g, ln2b, o);
  gate_kernel<<<NTOK, 256, 0, stream>>>(o, Wg, te, tv, inv);
  split_kernel<<<4096, 256, 0, stream>>>(o, bfAh, bfAl);   // ffin bf16 (hi used)
  route_sort_kernel<<<8, 1024, 0, stream>>>(te, tv, etok, ew, inv);
  // experts: up (gather + gelu -> bf16 h), down (-> bf16 eo; clobbers Vth/Vtl — dead)
  mgemm<2, true, false><<<dim3(32, 8, 8), 256, 0, stream>>>(
      bfAh, nullptr, W1t, nullptr, hbuf, b1, etok, 4096, 1024,
      0, 4096L * 1024, 1024L * 4096, 4096);
  mgemm<3, false, false><<<dim3(8, 8, 8), 256, 0, stream>>>(
      hbuf, nullptr, W2t, nullptr, eo, b2, nullptr, 1024, 4096,
      1024L * 4096, 1024L * 4096, 1024L * 1024, 1024);
  combine_kernel<<<NTOK, 256, 0, stream>>>(A, eo, inv, ew, out_x, out_aux);
}

// Round 5
// 818.857 us; speedup vs baseline: 1.1344x; 1.1344x over previous
//
#include <hip/hip_runtime.h>
#include <hip/hip_bf16.h>
#include <math.h>

// Round 5: split-KV flash attention (2560 partial blocks + deterministic merge),
// partials aliased into W1t region (weight tconv moved after merge),
// route_sort v2 (compaction + conditional small bitonic).
// B=2 T=2048 D=1024 NH=16 HD=64 HALF=32 NEXP=8 TOPK=2 CAP=1024 FF=4096

#define TT 2048
#define NTOK 4096

typedef __attribute__((ext_vector_type(8))) short bf16x8;
typedef __attribute__((ext_vector_type(4))) float f32x4;

static __device__ __forceinline__ ushort f2bf(float f) {
  union { float f; unsigned u; } v; v.f = f;
  unsigned r = v.u + 0x7FFFu + ((v.u >> 16) & 1u);
  return (ushort)(r >> 16);
}
static __device__ __forceinline__ float bf2f(ushort h) {
  union { unsigned u; float f; } v; v.u = ((unsigned)h) << 16; return v.f;
}

// ---------------------------------------------------------------- LayerNorm
__global__ __launch_bounds__(256)
void ln_kernel(const float* __restrict__ x, const float* __restrict__ g,
               const float* __restrict__ b, float* __restrict__ out) {
  int row = blockIdx.x, tid = threadIdx.x;
  const float4* xr = (const float4*)(x + (size_t)row * 1024);
  float4 v = xr[tid];
  float s = v.x + v.y + v.z + v.w;
  #pragma unroll
  for (int off = 1; off < 64; off <<= 1) s += __shfl_xor(s, off);
  __shared__ float red1[4], red2[4];
  if ((tid & 63) == 0) red1[tid >> 6] = s;
  __syncthreads();
  float mu = (red1[0] + red1[1] + red1[2] + red1[3]) * (1.0f / 1024.0f);
  float dx = v.x - mu, dy = v.y - mu, dz = v.z - mu, dw = v.w - mu;
  float ss = dx*dx + dy*dy + dz*dz + dw*dw;
  #pragma unroll
  for (int off = 1; off < 64; off <<= 1) ss += __shfl_xor(ss, off);
  if ((tid & 63) == 0) red2[tid >> 6] = ss;
  __syncthreads();
  float var = (red2[0] + red2[1] + red2[2] + red2[3]) * (1.0f / 1024.0f);
  float inv = 1.0f / sqrtf(var + 1e-5f);
  float4 g4 = ((const float4*)g)[tid];
  float4 b4 = ((const float4*)b)[tid];
  float4 o4;
  o4.x = dx * inv * g4.x + b4.x;
  o4.y = dy * inv * g4.y + b4.y;
  o4.z = dz * inv * g4.z + b4.z;
  o4.w = dw * inv * g4.w + b4.w;
  ((float4*)(out + (size_t)row * 1024))[tid] = o4;
}

// ---------------------------------------------------------------- RoPE tables (f64)
__global__ void sincos_kernel(float* __restrict__ st, float* __restrict__ ct) {
  int t = blockIdx.x, j = threadIdx.x;
  double invf = pow(10000.0, -((double)(2 * j)) / 64.0);
  double ang = (double)t * invf;
  st[t * 32 + j] = (float)sin(ang);
  ct[t * 32 + j] = (float)cos(ang);
}

// ---------------------------------------------------------------- RoPE apply + k,v outputs + Kh/Kl prep
__global__ __launch_bounds__(256)
void rope_kernel(float* __restrict__ qkv, const float* __restrict__ st,
                 const float* __restrict__ ct, float* __restrict__ kout,
                 float* __restrict__ vout, ushort* __restrict__ Kh,
                 ushort* __restrict__ Kl) {
  int row = blockIdx.x;
  int t = row & (TT - 1);
  int b = row >> 11;
  int tid = threadIdx.x;
  float* base = qkv + (size_t)row * 3072;
  #pragma unroll
  for (int l = 0; l < 2; ++l) {
    int idx = l * 256 + tid;
    int h = idx >> 5, j = idx & 31;
    float s = st[t * 32 + j], c = ct[t * 32 + j];
    float* qp = base + h * 192;
    float q1 = qp[j], q2 = qp[j + 32];
    qp[j]      = q1 * c - q2 * s;
    qp[j + 32] = q1 * s + q2 * c;
    float k1 = qp[64 + j], k2 = qp[96 + j];
    float kr1 = k1 * c - k2 * s, kr2 = k1 * s + k2 * c;
    qp[64 + j] = kr1; qp[96 + j] = kr2;
    kout[(size_t)row * 1024 + h * 64 + j]      = kr1;
    kout[(size_t)row * 1024 + h * 64 + 32 + j] = kr2;
    size_t kb = ((size_t)(b * 16 + h) * TT + t) * 64;
    ushort h1 = f2bf(kr1);
    Kh[kb + j] = h1; Kl[kb + j] = f2bf(kr1 - bf2f(h1));
    ushort h2 = f2bf(kr2);
    Kh[kb + 32 + j] = h2; Kl[kb + 32 + j] = f2bf(kr2 - bf2f(h2));
  }
  #pragma unroll
  for (int l = 0; l < 4; ++l) {
    int f = l * 256 + tid;
    int h = f >> 6, d = f & 63;
    vout[(size_t)row * 1024 + f] = base[h * 192 + 128 + d];
  }
}

// ---------------------------------------------------------------- V^T prep: [b,t,h*64] f32 -> [b,h,64,t] bf16 hi/lo
__global__ __launch_bounds__(256)
void vtprep_kernel(const float* __restrict__ vout, ushort* __restrict__ Vth,
                   ushort* __restrict__ Vtl) {
  __shared__ float tile[64][65];
  int t0 = blockIdx.x * 64, h = blockIdx.y, b = blockIdx.z;
  int tid = threadIdx.x;
  #pragma unroll
  for (int l = 0; l < 4; ++l) {
    int idx = l * 256 + tid;
    int r = idx >> 4, c4 = (idx & 15) * 4;
    *(float4*)&tile[r][c4] = *(const float4*)&vout[((size_t)(b * TT + t0 + r)) * 1024 + h * 64 + c4];
  }
  __syncthreads();
  int d = tid >> 2, ts = (tid & 3) * 16;
  union { bf16x8 v; ushort u[8]; } H0, H1, L0, L1;
  #pragma unroll
  for (int i = 0; i < 8; ++i) {
    float v0 = tile[ts + i][d];
    ushort hb0 = f2bf(v0);
    H0.u[i] = hb0; L0.u[i] = f2bf(v0 - bf2f(hb0));
    float v1 = tile[ts + 8 + i][d];
    ushort hb1 = f2bf(v1);
    H1.u[i] = hb1; L1.u[i] = f2bf(v1 - bf2f(hb1));
  }
  size_t basep = ((size_t)(b * 16 + h) * 64 + d) * TT + t0 + ts;
  *(bf16x8*)(Vth + basep) = H0.v;  *(bf16x8*)(Vth + basep + 8) = H1.v;
  *(bf16x8*)(Vtl + basep) = L0.v;  *(bf16x8*)(Vtl + basep + 8) = L1.v;
}

// ---------------------------------------------------------------- flash v5: split-KV partials
// block = (b,h, qt, kc): KV chunk of 8 kt-tiles (512 kv). Writes unnormalized
// partial O[64][64] + per-row m,l. XCD-swizzled, qt-descending per XCD.
__global__ __launch_bounds__(256)
void flash5_kernel(const float* __restrict__ qkv, const ushort* __restrict__ Kh,
                   const ushort* __restrict__ Kl, const ushort* __restrict__ Vth,
                   const ushort* __restrict__ Vtl, float* __restrict__ Opart,
                   float* __restrict__ Mpart, float* __restrict__ Lpart) {
  int lin = blockIdx.x;                     // 2560
  int xcd = lin & 7, q8 = lin >> 3;         // q8 in [0,320)
  int bh = xcd + 8 * (q8 / 80);
  int w = 79 - (q8 % 80);                   // long (high-qt) jobs first per XCD
  int qt, kc;
  if (w < 8)       { qt = w;                    kc = 0; }
  else if (w < 24) { qt = 8 + ((w - 8) >> 1);   kc = (w - 8) & 1; }
  else if (w < 48) { qt = 16 + (w - 24) / 3;    kc = (w - 24) % 3; }
  else             { qt = 24 + ((w - 48) >> 2); kc = (w - 48) & 3; }
  int slot = bh * 80 + w;
  int h = bh & 15, b = bh >> 4;
  int tid = threadIdx.x;
  int wv = tid >> 6, lane = tid & 63;
  int lr = lane & 15, lk = lane >> 4;
  size_t bT = (size_t)b * TT;
  int q0 = qt * 64;
  int qg = q0 + wv * 16 + lr;
  // Q fragments (B-operand), hi/lo split: d = kst*32 + lk*8 + j
  bf16x8 qh[2], ql[2];
  {
    const float* qp = qkv + (bT + qg) * 3072 + h * 192;
    #pragma unroll
    for (int kst = 0; kst < 2; ++kst) {
      float4 a = *(const float4*)(qp + kst * 32 + lk * 8);
      float4 bq = *(const float4*)(qp + kst * 32 + lk * 8 + 4);
      float vals[8] = {a.x, a.y, a.z, a.w, bq.x, bq.y, bq.z, bq.w};
      union { bf16x8 v; ushort u[8]; } H, L;
      #pragma unroll
      for (int j = 0; j < 8; ++j) {
        ushort hb = f2bf(vals[j]);
        H.u[j] = hb; L.u[j] = f2bf(vals[j] - bf2f(hb));
      }
      qh[kst] = H.v; ql[kst] = L.v;
    }
  }
  const ushort* Kbh = Kh + (size_t)(b * 16 + h) * TT * 64;
  const ushort* Kbl = Kl + (size_t)(b * 16 + h) * TT * 64;
  const ushort* Vbh = Vth + (size_t)(b * 16 + h) * 64 * TT;
  const ushort* Vbl = Vtl + (size_t)(b * 16 + h) * 64 * TT;
  f32x4 accO[4] = {};
  float m = -3.402823466e38f, lsum = 0.0f;
  int kt0 = kc * 8, kt1 = min(kt0 + 8, qt + 1);

  for (int kt = kt0; kt < kt1; ++kt) {
    bf16x8 kfh[2][4], kfl[2][4];
    #pragma unroll
    for (int kst = 0; kst < 2; ++kst)
      #pragma unroll
      for (int mf = 0; mf < 4; ++mf) {
        size_t ad = (size_t)(kt * 64 + mf * 16 + lr) * 64 + kst * 32 + lk * 8;
        kfh[kst][mf] = *(const bf16x8*)(Kbh + ad);
        kfl[kst][mf] = *(const bf16x8*)(Kbl + ad);
      }
    f32x4 accS[4] = {};
    #pragma unroll
    for (int kst = 0; kst < 2; ++kst) {
      #pragma unroll
      for (int mf = 0; mf < 4; ++mf)
        accS[mf] = __builtin_amdgcn_mfma_f32_16x16x32_bf16(kfh[kst][mf], qh[kst], accS[mf], 0, 0, 0);
      #pragma unroll
      for (int mf = 0; mf < 4; ++mf)
        accS[mf] = __builtin_amdgcn_mfma_f32_16x16x32_bf16(kfh[kst][mf], ql[kst], accS[mf], 0, 0, 0);
      #pragma unroll
      for (int mf = 0; mf < 4; ++mf)
        accS[mf] = __builtin_amdgcn_mfma_f32_16x16x32_bf16(kfl[kst][mf], qh[kst], accS[mf], 0, 0, 0);
    }
    float pmax = -3.402823466e38f;
    if (kt == qt) {
      #pragma unroll
      for (int mf = 0; mf < 4; ++mf)
        #pragma unroll
        for (int r = 0; r < 4; ++r) {
          int kvg = kt * 64 + mf * 16 + lk * 4 + r;
          float sv = (kvg <= qg) ? accS[mf][r] * 0.125f : -3.402823466e38f;
          accS[mf][r] = sv;
          pmax = fmaxf(pmax, sv);
        }
    } else {
      #pragma unroll
      for (int mf = 0; mf < 4; ++mf)
        #pragma unroll
        for (int r = 0; r < 4; ++r) {
          float sv = accS[mf][r] * 0.125f;
          accS[mf][r] = sv;
          pmax = fmaxf(pmax, sv);
        }
    }
    pmax = fmaxf(pmax, __shfl_xor(pmax, 16));
    pmax = fmaxf(pmax, __shfl_xor(pmax, 32));
    float mnew = fmaxf(m, pmax);
    float fsc = __expf(m - mnew);
    float psum = 0.0f;
    #pragma unroll
    for (int mf = 0; mf < 4; ++mf)
      #pragma unroll
      for (int r = 0; r < 4; ++r) {
        float p = __expf(accS[mf][r] - mnew);
        accS[mf][r] = p;
        psum += p;
      }
    psum += __shfl_xor(psum, 16);
    psum += __shfl_xor(psum, 32);
    lsum = lsum * fsc + psum;
    m = mnew;
    bf16x8 vfh[2][4], vfl[2][4];
    #pragma unroll
    for (int kst = 0; kst < 2; ++kst)
      #pragma unroll
      for (int nf = 0; nf < 4; ++nf) {
        size_t ad = (size_t)(nf * 16 + lr) * TT + kt * 64 + kst * 32 + lk * 8;
        vfh[kst][nf] = *(const bf16x8*)(Vbh + ad);
        vfl[kst][nf] = *(const bf16x8*)(Vbl + ad);
      }
    #pragma unroll
    for (int r = 0; r < 4; ++r) {
      int srcF = (lane & 48) | (((lane >> 4) & 3) << 2) | r;
      float fr = __shfl(fsc, srcF);
      #pragma unroll
      for (int nf = 0; nf < 4; ++nf) accO[nf][r] *= fr;
    }
    #pragma unroll
    for (int kst = 0; kst < 2; ++kst) {
      float pj[8];
      #pragma unroll
      for (int j = 0; j < 8; ++j) {
        int src = ((((lane & 16) >> 3) + (j >> 2)) << 4) | lr;
        float v0 = __shfl(accS[kst * 2][j & 3], src);
        float v1 = __shfl(accS[kst * 2 + 1][j & 3], src);
        pj[j] = (lane & 32) ? v1 : v0;
      }
      union { bf16x8 v; ushort u[8]; } PH, PL;
      #pragma unroll
      for (int j = 0; j < 8; ++j) {
        ushort hb = f2bf(pj[j]);
        PH.u[j] = hb; PL.u[j] = f2bf(pj[j] - bf2f(hb));
      }
      #pragma unroll
      for (int nf = 0; nf < 4; ++nf)
        accO[nf] = __builtin_amdgcn_mfma_f32_16x16x32_bf16(PH.v, vfh[kst][nf], accO[nf], 0, 0, 0);
      #pragma unroll
      for (int nf = 0; nf < 4; ++nf)
        accO[nf] = __builtin_amdgcn_mfma_f32_16x16x32_bf16(PH.v, vfl[kst][nf], accO[nf], 0, 0, 0);
      #pragma unroll
      for (int nf = 0; nf < 4; ++nf)
        accO[nf] = __builtin_amdgcn_mfma_f32_16x16x32_bf16(PL.v, vfh[kst][nf], accO[nf], 0, 0, 0);
    }
  }
  // ---- partial epilogue (unnormalized)
  if (lk == 0) {
    Mpart[slot * 64 + wv * 16 + lr] = m;
    Lpart[slot * 64 + wv * 16 + lr] = lsum;
  }
  #pragma unroll
  for (int nf = 0; nf < 4; ++nf)
    #pragma unroll
    for (int r = 0; r < 4; ++r)
      Opart[(size_t)slot * 4096 + (wv * 16 + lk * 4 + r) * 64 + nf * 16 + lr] = accO[nf][r];
}

// ---------------------------------------------------------------- merge partials (deterministic, chunk-ascending)
__global__ __launch_bounds__(256)
void fmerge_kernel(const float* __restrict__ Opart, const float* __restrict__ Mpart,
                   const float* __restrict__ Lpart, float* __restrict__ o) {
  int qt = blockIdx.x, bh = blockIdx.y;
  int h = bh & 15, b = bh >> 4;
  int g = qt >> 3;
  int nc = g + 1;
  int w0 = ((g == 0) ? 0 : (g == 1) ? 8 : (g == 2) ? 24 : 48) + (qt - (g << 3)) * nc;
  int slot0 = bh * 80 + w0;
  int tid = threadIdx.x;
  int q = tid >> 2, d0 = (tid & 3) << 4;
  float mg = -3.402823466e38f;
  for (int c = 0; c < nc; ++c) mg = fmaxf(mg, Mpart[(slot0 + c) * 64 + q]);
  float lg = 0.0f;
  float4 acc[4] = {};
  for (int c = 0; c < nc; ++c) {
    float sc = __expf(Mpart[(slot0 + c) * 64 + q] - mg);
    lg += sc * Lpart[(slot0 + c) * 64 + q];
    const float4* op = (const float4*)(Opart + (size_t)(slot0 + c) * 4096 + q * 64 + d0);
    #pragma unroll
    for (int i = 0; i < 4; ++i) {
      float4 v = op[i];
      acc[i].x += sc * v.x; acc[i].y += sc * v.y;
      acc[i].z += sc * v.z; acc[i].w += sc * v.w;
    }
  }
  float inv = 1.0f / lg;
  float* obase = o + ((size_t)(b * TT + qt * 64 + q)) * 1024 + h * 64 + d0;
  #pragma unroll
  for (int i = 0; i < 4; ++i) {
    float4 v = {acc[i].x * inv, acc[i].y * inv, acc[i].z * inv, acc[i].w * inv};
    *(float4*)(obase + i * 4) = v;
  }
}

// ---------------------------------------------------------------- transpose + bf16 convert (+lo split)
template<bool LO>
__global__ void tconv_kernel(const float* __restrict__ in, ushort* __restrict__ oh,
                             ushort* __restrict__ ol, int K, int N) {
  __shared__ float t[32][33];
  int z = blockIdx.z;
  const float* ip = in + (size_t)z * K * N;
  ushort* ohp = oh + (size_t)z * K * N;
  ushort* olp = LO ? (ol + (size_t)z * K * N) : nullptr;
  int n0 = blockIdx.x * 32, k0 = blockIdx.y * 32;
  int tx = threadIdx.x, ty = threadIdx.y;   // (32,8)
  #pragma unroll
  for (int i = 0; i < 4; ++i)
    t[ty + 8 * i][tx] = ip[(size_t)(k0 + ty + 8 * i) * N + n0 + tx];
  __syncthreads();
  #pragma unroll
  for (int i = 0; i < 4; ++i) {
    float v = t[tx][ty + 8 * i];
    size_t off = (size_t)(n0 + ty + 8 * i) * K + k0 + tx;
    ushort hb = f2bf(v);
    ohp[off] = hb;
    if (LO) olp[off] = f2bf(v - bf2f(hb));
  }
}

// ---------------------------------------------------------------- rowwise hi/lo bf16 split
__global__ __launch_bounds__(256)
void split_kernel(const float* __restrict__ in, ushort* __restrict__ oh,
                  ushort* __restrict__ ol) {
  size_t i = ((size_t)blockIdx.x * 256 + threadIdx.x) * 4;
  float4 v = *(const float4*)(in + i);
  ushort h0 = f2bf(v.x), h1 = f2bf(v.y), h2 = f2bf(v.z), h3 = f2bf(v.w);
  ushort4 hh = {h0, h1, h2, h3};
  *(ushort4*)(oh + i) = hh;
  ushort4 ll = {f2bf(v.x - bf2f(h0)), f2bf(v.y - bf2f(h1)),
                f2bf(v.z - bf2f(h2)), f2bf(v.w - bf2f(h3))};
  *(ushort4*)(ol + i) = ll;
}

// ---------------------------------------------------------------- MFMA GEMM (unchanged)
#define LOAD_STEP(tt) do {                                                     \
    int seg = SPLIT3 ? ((tt) / kPer) : 0;                                      \
    int kk = (SPLIT3 ? ((tt) % kPer) : (tt)) << 6;                             \
    const ushort* Ause = (SPLIT3 && seg == 2) ? AlB : AhB;                     \
    const ushort* Buse = (SPLIT3 && seg == 1) ? BlB : BhB;                     \
    _Pragma("unroll")                                                          \
    for (int q = 0; q < 4; ++q) {                                              \
      int rr = r0 + 32 * q;                                                    \
      int clog = cph ^ (rr & 7);                                               \
      ra[q] = *(const bf16x8*)(Ause + (size_t)garow[q] * K + kk + clog * 8);   \
      rb[q] = *(const bf16x8*)(Buse + (size_t)(bn + rr) * K + kk + clog * 8);  \
    }                                                                          \
  } while (0)

template<int EPI, bool GATHER, bool SPLIT3>
__global__ __launch_bounds__(256, 2)
void mgemm(const ushort* __restrict__ Ah, const ushort* __restrict__ Al,
           const ushort* __restrict__ Bh, const ushort* __restrict__ Bl,
           void* __restrict__ Cv, const float* __restrict__ extra,
           const int* __restrict__ gatAll, int N, int K,
           long aEStride, long bEStride, long cEStride, int biasEStride) {
  __shared__ ushort As[128 * 64];
  __shared__ ushort Bs[128 * 64];
  int z = blockIdx.z;
  const ushort* AhB = Ah + (size_t)z * aEStride;
  const ushort* AlB = SPLIT3 ? (Al + (size_t)z * aEStride) : nullptr;
  const ushort* BhB = Bh + (size_t)z * bEStride;
  const ushort* BlB = SPLIT3 ? (Bl + (size_t)z * bEStride) : nullptr;
  const int* gat = GATHER ? (gatAll + z * 1024) : nullptr;
  int bm = blockIdx.y * 128, bn = blockIdx.x * 128;
  int tid = threadIdx.x;
  int r0 = tid >> 3, cph = tid & 7;
  int garow[4];
  #pragma unroll
  for (int q = 0; q < 4; ++q) {
    int rr = r0 + 32 * q;
    garow[q] = GATHER ? gat[bm + rr] : (bm + rr);
  }
  int kPer = K >> 6;
  int kSteps = (SPLIT3 ? 3 : 1) * kPer;
  int wid = tid >> 6, lane = tid & 63;
  int wm = wid >> 1, wn = wid & 1;
  int lr = lane & 15, lk = lane >> 4;
  f32x4 acc[4][4] = {};
  bf16x8 ra[4], rb[4];
  LOAD_STEP(0);
  for (int t = 0; t < kSteps; ++t) {
    __syncthreads();
    #pragma unroll
    for (int q = 0; q < 4; ++q) {
      int rr = r0 + 32 * q;
      *(bf16x8*)&As[rr * 64 + cph * 8] = ra[q];
      *(bf16x8*)&Bs[rr * 64 + cph * 8] = rb[q];
    }
    __syncthreads();
    if (t + 1 < kSteps) LOAD_STEP(t + 1);
    #pragma unroll
    for (int kh = 0; kh < 2; ++kh) {
      bf16x8 af[4], bfr[4];
      #pragma unroll
      for (int mf = 0; mf < 4; ++mf) {
        int row = wm * 64 + mf * 16 + lr;
        int ch = (kh * 4 + lk) ^ (row & 7);
        af[mf] = *(const bf16x8*)&As[row * 64 + ch * 8];
      }
      #pragma unroll
      for (int nf = 0; nf < 4; ++nf) {
        int row = wn * 64 + nf * 16 + lr;
        int ch = (kh * 4 + lk) ^ (row & 7);
        bfr[nf] = *(const bf16x8*)&Bs[row * 64 + ch * 8];
      }
      #pragma unroll
      for (int mf = 0; mf < 4; ++mf)
        #pragma unroll
        for (int nf = 0; nf < 4; ++nf)
          acc[mf][nf] = __builtin_amdgcn_mfma_f32_16x16x32_bf16(af[mf], bfr[nf], acc[mf][nf], 0, 0, 0);
    }
  }
  int crow = bm + wm * 64, ccol = bn + wn * 64;
  if constexpr (EPI <= 1) {
    float* C = (float*)Cv;
    #pragma unroll
    for (int mf = 0; mf < 4; ++mf)
      #pragma unroll
      for (int nf = 0; nf < 4; ++nf)
        #pragma unroll
        for (int r = 0; r < 4; ++r) {
          int row = crow + mf * 16 + lk * 4 + r;
          int col = ccol + nf * 16 + lr;
          float v = acc[mf][nf][r];
          if constexpr (EPI == 1) v += extra[(size_t)row * N + col];
          C[(size_t)row * N + col] = v;
        }
  } else {
    const float* bias = extra + (size_t)z * biasEStride;
    ushort* C = (ushort*)Cv + (size_t)z * cEStride;
    #pragma unroll
    for (int mf = 0; mf < 4; ++mf)
      #pragma unroll
      for (int nf = 0; nf < 4; ++nf)
        #pragma unroll
        for (int r = 0; r < 4; ++r) {
          int row = crow + mf * 16 + lk * 4 + r;
          int col = ccol + nf * 16 + lr;
          float v = acc[mf][nf][r] + bias[col];
          if constexpr (EPI == 2)
            v = 0.5f * v * (1.0f + erff(v * 0.70710678118654752f));
          C[(size_t)row * N + col] = f2bf(v);
        }
  }
}

// ---------------------------------------------------------------- gate: softmax + stable top-2
__global__ __launch_bounds__(256)
void gate_kernel(const float* __restrict__ ffin, const float* __restrict__ Wg,
                 int* __restrict__ te, float* __restrict__ tv, int* __restrict__ inv) {
  int token = blockIdx.x, tid = threadIdx.x;
  float acc[8] = {};
  const float* xr = ffin + (size_t)token * 1024;
  for (int i = tid; i < 1024; i += 256) {
    float xv = xr[i];
    const float4* wr = (const float4*)&Wg[i * 8];
    float4 w0 = wr[0], w1 = wr[1];
    acc[0] += xv * w0.x; acc[1] += xv * w0.y; acc[2] += xv * w0.z; acc[3] += xv * w0.w;
    acc[4] += xv * w1.x; acc[5] += xv * w1.y; acc[6] += xv * w1.z; acc[7] += xv * w1.w;
  }
  #pragma unroll
  for (int off = 1; off < 64; off <<= 1)
    #pragma unroll
    for (int q = 0; q < 8; ++q) acc[q] += __shfl_xor(acc[q], off);
  __shared__ float red[4][8];
  if ((tid & 63) == 0)
    #pragma unroll
    for (int q = 0; q < 8; ++q) red[tid >> 6][q] = acc[q];
  __syncthreads();
  if (tid == 0) {
    float g[8];
    #pragma unroll
    for (int q = 0; q < 8; ++q) g[q] = red[0][q] + red[1][q] + red[2][q] + red[3][q];
    float mx = g[0];
    #pragma unroll
    for (int q = 1; q < 8; ++q) mx = fmaxf(mx, g[q]);
    float sum = 0.0f;
    #pragma unroll
    for (int q = 0; q < 8; ++q) { g[q] = expf(g[q] - mx); sum += g[q]; }
    float inv_s = 1.0f / sum;
    #pragma unroll
    for (int q = 0; q < 8; ++q) g[q] *= inv_s;
    int e1 = 0; float v1 = g[0];
    for (int q = 1; q < 8; ++q) if (g[q] > v1) { v1 = g[q]; e1 = q; }
    int e2 = -1; float v2 = -1.0f;
    for (int q = 0; q < 8; ++q) { if (q == e1) continue; if (g[q] > v2) { v2 = g[q]; e2 = q; } }
    te[token * 2] = e1; te[token * 2 + 1] = e2;
    tv[token * 2] = v1; tv[token * 2 + 1] = v2;
    inv[token * 2] = -1; inv[token * 2 + 1] = -1;
  }
}

// ---------------------------------------------------------------- per-expert capacity select v2
// stable ballot compaction (slot-asc) -> skip sort if n<=1024, else bitonic on
// padded pow2 (<=4096). Selection is a SET (scatter-add is order-independent);
// ties at the boundary exact via 64-bit (value, ~slot) keys.
__global__ __launch_bounds__(1024)
void route_sort_kernel(const int* __restrict__ te, const float* __restrict__ tv,
                       int* __restrict__ etok, float* __restrict__ ew,
                       int* __restrict__ inv) {
  __shared__ unsigned long long sk[4096];
  __shared__ int wcnt[16];
  __shared__ int base;
  int e = blockIdx.x, tid = threadIdx.x;
  int lane = tid & 63, wv = tid >> 6;
  if (tid == 0) base = 0;
  __syncthreads();
  for (int c = 0; c < 8; ++c) {
    int s = c * 1024 + tid;
    bool sel = (te[s] == e);
    unsigned long long ball = __ballot(sel);
    int pre = __popcll(ball & ((1ull << lane) - 1ull));
    if (lane == 0) wcnt[wv] = __popcll(ball);
    __syncthreads();
    int woff = 0, tot = 0;
    #pragma unroll
    for (int i = 0; i < 16; ++i) {
      int cc = wcnt[i];
      if (i < wv) woff += cc;
      tot += cc;
    }
    if (sel) {
      unsigned vb = __float_as_uint(tv[s]);
      sk[base + woff + pre] =
          ((unsigned long long)vb << 32) | (unsigned)(0xFFFFFFFFu - (unsigned)s);
    }
    __syncthreads();
    if (tid == 0) base += tot;
    __syncthreads();
  }
  int n = base;
  if (n > 1024) {
    int P = (n <= 2048) ? 2048 : 4096;
    for (int i = n + tid; i < P; i += 1024) sk[i] = 0ull;
    __syncthreads();
    for (int k = 2; k <= P; k <<= 1)
      for (int j = k >> 1; j > 0; j >>= 1) {
        for (int t = tid; t < (P >> 1); t += 1024) {
          int i = ((t & ~(j - 1)) << 1) | (t & (j - 1));
          int p = i | j;
          unsigned long long a = sk[i], bq = sk[p];
          bool desc = ((i & k) == 0);
          if (desc ? (a < bq) : (a > bq)) { sk[i] = bq; sk[p] = a; }
        }
        __syncthreads();
      }
  }
  int cap = n < 1024 ? n : 1024;
  if (tid < cap) {
    unsigned long long key = sk[tid];
    unsigned slot = 0xFFFFFFFFu - (unsigned)(key & 0xFFFFFFFFull);
    etok[e * 1024 + tid] = (int)(slot >> 1);
    ew[e * 1024 + tid] = __uint_as_float((unsigned)(key >> 32));
    inv[slot] = e * 1024 + tid;
  } else {
    etok[e * 1024 + tid] = 0;
    ew[e * 1024 + tid] = 0.0f;
  }
}

// ---------------------------------------------------------------- final combine (deterministic)
__global__ __launch_bounds__(256)
void combine_kernel(const float* __restrict__ xres, const ushort* __restrict__ eo,
                    const int* __restrict__ inv, const float* __restrict__ ew,
                    float* __restrict__ outx, float* __restrict__ aux) {
  int token = blockIdx.x;
  int d = threadIdx.x * 4;
  float4 acc = *(const float4*)&xres[(size_t)token * 1024 + d];
  #pragma unroll
  for (int j = 0; j < 2; ++j) {
    int p = inv[token * 2 + j];
    if (p >= 0) {
      float w = ew[p];
      const ushort* ep = eo + (size_t)p * 1024 + d;
      acc.x += w * bf2f(ep[0]); acc.y += w * bf2f(ep[1]);
      acc.z += w * bf2f(ep[2]); acc.w += w * bf2f(ep[3]);
    }
  }
  *(float4*)&outx[(size_t)token * 1024 + d] = acc;
  if (token == 0 && threadIdx.x == 0) aux[0] = 0.0f;
}

// ================================================================ launch
extern "C" void kernel_launch(void* const* d_in, const int* in_sizes, int n_in,
                              void* d_out, int out_size, void* d_ws, size_t ws_size,
                              hipStream_t stream) {
  const float* x     = (const float*)d_in[0];
  const float* ln1g  = (const float*)d_in[1];
  const float* ln1b  = (const float*)d_in[2];
  const float* ln2g  = (const float*)d_in[3];
  const float* ln2b  = (const float*)d_in[4];
  const float* Wqkv  = (const float*)d_in[5];
  const float* Wproj = (const float*)d_in[6];
  const float* Wg    = (const float*)d_in[7];
  const float* W1    = (const float*)d_in[8];
  const float* b1    = (const float*)d_in[9];
  const float* W2    = (const float*)d_in[10];
  const float* b2    = (const float*)d_in[11];

  float* out_x   = (float*)d_out;
  float* out_aux = out_x + 4194304;
  float* out_k   = out_aux + 1;
  float* out_v   = out_k + 4194304;

  float* ws   = (float*)d_ws;
  float* A    = ws;                          // x_norm -> x_res
  float* qkvb = ws + 4194304;                // fp32 qkv (aliased by h later)
  float* o    = ws + 16777216;               // attn out -> ff_in
  float* st   = ws + 20971520;
  float* ct   = ws + 21037056;
  int*   te   = (int*)(ws + 21102592);
  float* tv   = ws + 21110784;
  int*   etok = (int*)(ws + 21118976);
  float* ew   = ws + 21127168;
  int*   inv  = (int*)(ws + 21135360);
  ushort* bfAh = (ushort*)(ws + 21143552);   // [4096][1024] bf16
  ushort* bfAl = (ushort*)(ws + 23240704);
  ushort* BqH  = (ushort*)(ws + 25337856);   // WqkvT hi [3072][1024]
  ushort* BqL  = (ushort*)(ws + 26910720);
  ushort* BpH  = (ushort*)(ws + 28483584);   // WprojT hi [1024][1024]
  ushort* BpL  = (ushort*)(ws + 29007872);
  ushort* W1t  = (ushort*)(ws + 29532160);   // [8][4096][1024] (written AFTER fmerge)
  ushort* W2t  = (ushort*)(ws + 46309376);   // [8][1024][4096]
  ushort* eo   = (ushort*)(ws + 63086592);   // [8192][1024] bf16
  ushort* hbuf = (ushort*)(ws + 4194304);    // [8][1024][4096] bf16, aliases qkvb+o
  // flash operand buffers (aliased into dead regions during attention):
  ushort* Kh_  = bfAh;                       // [2][16][2048][64]
  ushort* Kl_  = bfAl;
  ushort* Vth_ = eo;                         // [2][16][64][2048]
  ushort* Vtl_ = eo + 4194304;
  // split-KV partials alias the (not-yet-written) W1t region:
  float* Opart = ws + 29532160;              // [2560][64][64]
  float* Mpart = ws + 40017920;              // [2560][64]
  float* Lpart = ws + 40181760;              // [2560][64]

  // weight prep needed before flash (W1/W2 transposes moved after fmerge)
  tconv_kernel<true ><<<dim3(96, 32, 1),  dim3(32, 8), 0, stream>>>(Wqkv,  BqH, BqL, 1024, 3072);
  tconv_kernel<true ><<<dim3(32, 32, 1),  dim3(32, 8), 0, stream>>>(Wproj, BpH, BpL, 1024, 1024);
  sincos_kernel<<<TT, 32, 0, stream>>>(st, ct);

  // LN1 + split
  ln_kernel<<<NTOK, 256, 0, stream>>>(x, ln1g, ln1b, A);
  split_kernel<<<4096, 256, 0, stream>>>(A, bfAh, bfAl);
  // QKV (split-bf16, K' = 3*1024)
  mgemm<0, false, true><<<dim3(24, 32, 1), 256, 0, stream>>>(
      bfAh, bfAl, BqH, BqL, qkvb, nullptr, nullptr, 3072, 1024, 0, 0, 0, 0);
  // RoPE + k/v outputs + Kh/Kl prep (bfAh/bfAl dead now)
  rope_kernel<<<NTOK, 256, 0, stream>>>(qkvb, st, ct, out_k, out_v, Kh_, Kl_);
  vtprep_kernel<<<dim3(32, 16, 2), 256, 0, stream>>>(out_v, Vth_, Vtl_);
  // split-KV flash + merge
  flash5_kernel<<<2560, 256, 0, stream>>>(qkvb, Kh_, Kl_, Vth_, Vtl_, Opart, Mpart, Lpart);
  fmerge_kernel<<<dim3(32, 32), 256, 0, stream>>>(Opart, Mpart, Lpart, o);
  // proj + residual (split-bf16; clobbers Kh/Kl — dead)
  split_kernel<<<4096, 256, 0, stream>>>(o, bfAh, bfAl);
  mgemm<1, false, true><<<dim3(8, 32, 1), 256, 0, stream>>>(
      bfAh, bfAl, BpH, BpL, A, x, nullptr, 1024, 1024, 0, 0, 0, 0);
  // expert weight prep (W1t region free again after fmerge)
  tconv_kernel<false><<<dim3(128, 32, 8), dim3(32, 8), 0, stream>>>(W1, W1t, nullptr, 1024, 4096);
  tconv_kernel<false><<<dim3(32, 128, 8), dim3(32, 8), 0, stream>>>(W2, W2t, nullptr, 4096, 1024);
  // LN2 -> ff_in (in o buffer), gate, route
  ln_kernel<<<NTOK, 256, 0, stream>>>(A, ln2g, ln2b, o);
  gate_kernel<<<NTOK, 256, 0, stream>>>(o, Wg, te, tv, inv);
  split_kernel<<<4096, 256, 0, stream>>>(o, bfAh, bfAl);   // ffin bf16 (hi used)
  route_sort_kernel<<<8, 1024, 0, stream>>>(te, tv, etok, ew, inv);
  // experts: up (gather + gelu -> bf16 h), down (-> bf16 eo; clobbers Vth/Vtl — dead)
  mgemm<2, true, false><<<dim3(32, 8, 8), 256, 0, stream>>>(
      bfAh, nullptr, W1t, nullptr, hbuf, b1, etok, 4096, 1024,
      0, 4096L * 1024, 1024L * 4096, 4096);
  mgemm<3, false, false><<<dim3(8, 8, 8), 256, 0, stream>>>(
      hbuf, nullptr, W2t, nullptr, eo, b2, nullptr, 1024, 4096,
      1024L * 4096, 1024L * 4096, 1024L * 1024, 1024);
  combine_kernel<<<NTOK, 256, 0, stream>>>(A, eo, inv, ew, out_x, out_aux);
}

// Round 6
// 699.295 us; speedup vs baseline: 1.3283x; 1.1710x over previous
//
#include <hip/hip_runtime.h>
#include <hip/hip_bf16.h>
#include <math.h>

// Round 6: flash6 = 32x32 swapped-QK MFMA attention, in-register softmax,
// cvt_pk+permlane32_swap P redistribution (no ds_bpermute), split-KV partials.
// B=2 T=2048 D=1024 NH=16 HD=64 HALF=32 NEXP=8 TOPK=2 CAP=1024 FF=4096

#define TT 2048
#define NTOK 4096

typedef __attribute__((ext_vector_type(8))) short bf16x8;
typedef __attribute__((ext_vector_type(4))) float f32x4;
typedef __attribute__((ext_vector_type(16))) float f32x16;

static __device__ __forceinline__ ushort f2bf(float f) {
  union { float f; unsigned u; } v; v.f = f;
  unsigned r = v.u + 0x7FFFu + ((v.u >> 16) & 1u);
  return (ushort)(r >> 16);
}
static __device__ __forceinline__ float bf2f(ushort h) {
  union { unsigned u; float f; } v; v.u = ((unsigned)h) << 16; return v.f;
}
static __device__ __forceinline__ unsigned cvt_pk_bf16(float lo, float hi) {
  unsigned r;
  asm("v_cvt_pk_bf16_f32 %0, %1, %2" : "=v"(r) : "v"(lo), "v"(hi));
  return r;
}
static __device__ __forceinline__ void plane_swap(unsigned& a, unsigned& b) {
  // a' = [a_lo31 | b_lo31], b' = [a_hi31 | b_hi31]
  asm("v_permlane32_swap_b32 %0, %1" : "+v"(a), "+v"(b));
}

// ---------------------------------------------------------------- LayerNorm
__global__ __launch_bounds__(256)
void ln_kernel(const float* __restrict__ x, const float* __restrict__ g,
               const float* __restrict__ b, float* __restrict__ out) {
  int row = blockIdx.x, tid = threadIdx.x;
  const float4* xr = (const float4*)(x + (size_t)row * 1024);
  float4 v = xr[tid];
  float s = v.x + v.y + v.z + v.w;
  #pragma unroll
  for (int off = 1; off < 64; off <<= 1) s += __shfl_xor(s, off);
  __shared__ float red1[4], red2[4];
  if ((tid & 63) == 0) red1[tid >> 6] = s;
  __syncthreads();
  float mu = (red1[0] + red1[1] + red1[2] + red1[3]) * (1.0f / 1024.0f);
  float dx = v.x - mu, dy = v.y - mu, dz = v.z - mu, dw = v.w - mu;
  float ss = dx*dx + dy*dy + dz*dz + dw*dw;
  #pragma unroll
  for (int off = 1; off < 64; off <<= 1) ss += __shfl_xor(ss, off);
  if ((tid & 63) == 0) red2[tid >> 6] = ss;
  __syncthreads();
  float var = (red2[0] + red2[1] + red2[2] + red2[3]) * (1.0f / 1024.0f);
  float inv = 1.0f / sqrtf(var + 1e-5f);
  float4 g4 = ((const float4*)g)[tid];
  float4 b4 = ((const float4*)b)[tid];
  float4 o4;
  o4.x = dx * inv * g4.x + b4.x;
  o4.y = dy * inv * g4.y + b4.y;
  o4.z = dz * inv * g4.z + b4.z;
  o4.w = dw * inv * g4.w + b4.w;
  ((float4*)(out + (size_t)row * 1024))[tid] = o4;
}

// ---------------------------------------------------------------- RoPE tables (f64)
__global__ void sincos_kernel(float* __restrict__ st, float* __restrict__ ct) {
  int t = blockIdx.x, j = threadIdx.x;
  double invf = pow(10000.0, -((double)(2 * j)) / 64.0);
  double ang = (double)t * invf;
  st[t * 32 + j] = (float)sin(ang);
  ct[t * 32 + j] = (float)cos(ang);
}

// ---------------------------------------------------------------- RoPE apply + k,v outputs + Kh/Kl prep
__global__ __launch_bounds__(256)
void rope_kernel(float* __restrict__ qkv, const float* __restrict__ st,
                 const float* __restrict__ ct, float* __restrict__ kout,
                 float* __restrict__ vout, ushort* __restrict__ Kh,
                 ushort* __restrict__ Kl) {
  int row = blockIdx.x;
  int t = row & (TT - 1);
  int b = row >> 11;
  int tid = threadIdx.x;
  float* base = qkv + (size_t)row * 3072;
  #pragma unroll
  for (int l = 0; l < 2; ++l) {
    int idx = l * 256 + tid;
    int h = idx >> 5, j = idx & 31;
    float s = st[t * 32 + j], c = ct[t * 32 + j];
    float* qp = base + h * 192;
    float q1 = qp[j], q2 = qp[j + 32];
    qp[j]      = q1 * c - q2 * s;
    qp[j + 32] = q1 * s + q2 * c;
    float k1 = qp[64 + j], k2 = qp[96 + j];
    float kr1 = k1 * c - k2 * s, kr2 = k1 * s + k2 * c;
    qp[64 + j] = kr1; qp[96 + j] = kr2;
    kout[(size_t)row * 1024 + h * 64 + j]      = kr1;
    kout[(size_t)row * 1024 + h * 64 + 32 + j] = kr2;
    size_t kb = ((size_t)(b * 16 + h) * TT + t) * 64;
    ushort h1 = f2bf(kr1);
    Kh[kb + j] = h1; Kl[kb + j] = f2bf(kr1 - bf2f(h1));
    ushort h2 = f2bf(kr2);
    Kh[kb + 32 + j] = h2; Kl[kb + 32 + j] = f2bf(kr2 - bf2f(h2));
  }
  #pragma unroll
  for (int l = 0; l < 4; ++l) {
    int f = l * 256 + tid;
    int h = f >> 6, d = f & 63;
    vout[(size_t)row * 1024 + f] = base[h * 192 + 128 + d];
  }
}

// ---------------------------------------------------------------- V^T prep: [b,t,h*64] f32 -> [b,h,64,t] bf16 hi/lo
__global__ __launch_bounds__(256)
void vtprep_kernel(const float* __restrict__ vout, ushort* __restrict__ Vth,
                   ushort* __restrict__ Vtl) {
  __shared__ float tile[64][65];
  int t0 = blockIdx.x * 64, h = blockIdx.y, b = blockIdx.z;
  int tid = threadIdx.x;
  #pragma unroll
  for (int l = 0; l < 4; ++l) {
    int idx = l * 256 + tid;
    int r = idx >> 4, c4 = (idx & 15) * 4;
    *(float4*)&tile[r][c4] = *(const float4*)&vout[((size_t)(b * TT + t0 + r)) * 1024 + h * 64 + c4];
  }
  __syncthreads();
  int d = tid >> 2, ts = (tid & 3) * 16;
  union { bf16x8 v; ushort u[8]; } H0, H1, L0, L1;
  #pragma unroll
  for (int i = 0; i < 8; ++i) {
    float v0 = tile[ts + i][d];
    ushort hb0 = f2bf(v0);
    H0.u[i] = hb0; L0.u[i] = f2bf(v0 - bf2f(hb0));
    float v1 = tile[ts + 8 + i][d];
    ushort hb1 = f2bf(v1);
    H1.u[i] = hb1; L1.u[i] = f2bf(v1 - bf2f(hb1));
  }
  size_t basep = ((size_t)(b * 16 + h) * 64 + d) * TT + t0 + ts;
  *(bf16x8*)(Vth + basep) = H0.v;  *(bf16x8*)(Vth + basep + 8) = H1.v;
  *(bf16x8*)(Vtl + basep) = L0.v;  *(bf16x8*)(Vtl + basep + 8) = L1.v;
}

// ---------------------------------------------------------------- flash v6 (32x32 swapped-QK, split-KV)
// job = (bh, qt of 128 rows, kc of 512 kv). 4 waves, wave w owns q-subtile of 32.
// S^T = mfma_32x32x16(K, Q^T): lane col = q, rows = kv -> lane-pair owns a P-row.
// PV: O^T = mfma(V^T, P^T): P^T B-frags built via cvt_pk + permlane32_swap.
__global__ __launch_bounds__(256)
void flash6_kernel(const float* __restrict__ qkv, const ushort* __restrict__ Kh,
                   const ushort* __restrict__ Kl, const ushort* __restrict__ Vth,
                   const ushort* __restrict__ Vtl, float* __restrict__ Opart,
                   float* __restrict__ Mpart, float* __restrict__ Lpart) {
  int lin = blockIdx.x;                     // 1280
  int xcd = lin & 7, s = lin >> 3;          // s in [0,160)
  int bh = xcd + 8 * (s / 40);
  int j = 39 - (s % 40);                    // long (high-qt) jobs first per XCD
  int qt, kc;
  if (j < 4)       { qt = j;                    kc = 0; }
  else if (j < 12) { qt = 4 + ((j - 4) >> 1);   kc = (j - 4) & 1; }
  else if (j < 24) { qt = 8 + (j - 12) / 3;     kc = (j - 12) % 3; }
  else             { qt = 12 + ((j - 24) >> 2); kc = (j - 24) & 3; }
  int slot = bh * 40 + j;
  int h = bh & 15, b = bh >> 4;
  int tid = threadIdx.x;
  int w = tid >> 6, lane = tid & 63;
  int q = lane & 31, LH = lane >> 5;        // q = MFMA col; LH = lane half
  size_t bT = (size_t)b * TT;
  int qglob0 = qt * 128 + w * 32;
  int qg = qglob0 + q;
  // Q^T B-frags (hi/lo split): B[k=d][col=q], d = dblk*16 + LH*8 + j
  bf16x8 qH[4], qL[4];
  {
    const float* qp = qkv + (bT + qg) * 3072 + h * 192 + LH * 8;
    #pragma unroll
    for (int dblk = 0; dblk < 4; ++dblk) {
      float4 f0 = *(const float4*)(qp + dblk * 16);
      float4 f1 = *(const float4*)(qp + dblk * 16 + 4);
      float vals[8] = {f0.x, f0.y, f0.z, f0.w, f1.x, f1.y, f1.z, f1.w};
      union { bf16x8 v; ushort u[8]; } H, L;
      #pragma unroll
      for (int e = 0; e < 8; ++e) {
        ushort hb = f2bf(vals[e]);
        H.u[e] = hb; L.u[e] = f2bf(vals[e] - bf2f(hb));
      }
      qH[dblk] = H.v; qL[dblk] = L.v;
    }
  }
  const ushort* Kbh = Kh + (size_t)bh * TT * 64;
  const ushort* Kbl = Kl + (size_t)bh * TT * 64;
  const ushort* Vbh = Vth + (size_t)bh * 64 * TT;
  const ushort* Vbl = Vtl + (size_t)bh * 64 * TT;
  f32x16 accO0 = {}, accO1 = {};            // O^T: col=q, rows d (accO1: d+32)
  float m = -3.402823466e38f, lsum = 0.0f;
  int kvlo = kc * 512;
  int kvhi = min(kc * 512 + 512, qglob0 + 32);

  for (int kv0 = kvlo; kv0 < kvhi; kv0 += 32) {
    // K A-frags: A[row=kv=lane&31][k=d]
    const ushort* kbh = Kbh + (size_t)(kv0 + q) * 64 + LH * 8;
    const ushort* kbl = Kbl + (size_t)(kv0 + q) * 64 + LH * 8;
    bf16x8 kAH[4], kAL[4];
    #pragma unroll
    for (int dblk = 0; dblk < 4; ++dblk) {
      kAH[dblk] = *(const bf16x8*)(kbh + dblk * 16);
      kAL[dblk] = *(const bf16x8*)(kbl + dblk * 16);
    }
    // QK^T: two independent 6-chains (dblk 0-1 vs 2-3)
    f32x16 sa = {}, sb = {};
    sa = __builtin_amdgcn_mfma_f32_32x32x16_bf16(kAH[0], qH[0], sa, 0, 0, 0);
    sb = __builtin_amdgcn_mfma_f32_32x32x16_bf16(kAH[2], qH[2], sb, 0, 0, 0);
    sa = __builtin_amdgcn_mfma_f32_32x32x16_bf16(kAH[1], qH[1], sa, 0, 0, 0);
    sb = __builtin_amdgcn_mfma_f32_32x32x16_bf16(kAH[3], qH[3], sb, 0, 0, 0);
    sa = __builtin_amdgcn_mfma_f32_32x32x16_bf16(kAH[0], qL[0], sa, 0, 0, 0);
    sb = __builtin_amdgcn_mfma_f32_32x32x16_bf16(kAH[2], qL[2], sb, 0, 0, 0);
    sa = __builtin_amdgcn_mfma_f32_32x32x16_bf16(kAH[1], qL[1], sa, 0, 0, 0);
    sb = __builtin_amdgcn_mfma_f32_32x32x16_bf16(kAH[3], qL[3], sb, 0, 0, 0);
    sa = __builtin_amdgcn_mfma_f32_32x32x16_bf16(kAL[0], qH[0], sa, 0, 0, 0);
    sb = __builtin_amdgcn_mfma_f32_32x32x16_bf16(kAL[2], qH[2], sb, 0, 0, 0);
    sa = __builtin_amdgcn_mfma_f32_32x32x16_bf16(kAL[1], qH[1], sa, 0, 0, 0);
    sb = __builtin_amdgcn_mfma_f32_32x32x16_bf16(kAL[3], qH[3], sb, 0, 0, 0);
    // V^T A-frags (issue early): A[row=d=lane&31][k=kv]
    bf16x8 vAH[2][2], vAL[2][2];
    #pragma unroll
    for (int dblk = 0; dblk < 2; ++dblk)
      #pragma unroll
      for (int s2 = 0; s2 < 2; ++s2) {
        size_t ad = (size_t)(dblk * 32 + q) * TT + kv0 + s2 * 16 + LH * 8;
        vAH[dblk][s2] = *(const bf16x8*)(Vbh + ad);
        vAL[dblk][s2] = *(const bf16x8*)(Vbl + ad);
      }
    // scale + (diagonal) mask; p[r] at kv = kv0 + (r&3)+8*(r>>2)+4*LH
    float p[16];
    float pmax = -3.402823466e38f;
    if (kv0 + 31 > qglob0) {
      #pragma unroll
      for (int r = 0; r < 16; ++r) {
        int kvg = kv0 + (r & 3) + 8 * (r >> 2) + 4 * LH;
        float sv = (kvg <= qg) ? (sa[r] + sb[r]) * 0.125f : -3.402823466e38f;
        p[r] = sv; pmax = fmaxf(pmax, sv);
      }
    } else {
      #pragma unroll
      for (int r = 0; r < 16; ++r) {
        float sv = (sa[r] + sb[r]) * 0.125f;
        p[r] = sv; pmax = fmaxf(pmax, sv);
      }
    }
    pmax = fmaxf(pmax, __shfl_xor(pmax, 32));
    float mnew = fmaxf(m, pmax);
    float fsc = __expf(m - mnew);
    float psum = 0.0f;
    #pragma unroll
    for (int r = 0; r < 16; ++r) { p[r] = __expf(p[r] - mnew); psum += p[r]; }
    psum += __shfl_xor(psum, 32);
    lsum = lsum * fsc + psum;
    m = mnew;
    #pragma unroll
    for (int r = 0; r < 16; ++r) { accO0[r] *= fsc; accO1[r] *= fsc; }
    // P^T B-frags: k = s2*16 + LH*8 + j. cvt_pk pairs + permlane32_swap.
    bf16x8 pHf[2], pLf[2];
    #pragma unroll
    for (int s2 = 0; s2 < 2; ++s2) {
      int s8 = s2 * 8;
      unsigned a  = cvt_pk_bf16(p[s8 + 0], p[s8 + 1]);
      unsigned bw = cvt_pk_bf16(p[s8 + 2], p[s8 + 3]);
      unsigned c  = cvt_pk_bf16(p[s8 + 4], p[s8 + 5]);
      unsigned d  = cvt_pk_bf16(p[s8 + 6], p[s8 + 7]);
      float l0 = p[s8 + 0] - __uint_as_float(a << 16);
      float l1 = p[s8 + 1] - __uint_as_float(a & 0xFFFF0000u);
      float l2 = p[s8 + 2] - __uint_as_float(bw << 16);
      float l3 = p[s8 + 3] - __uint_as_float(bw & 0xFFFF0000u);
      float l4 = p[s8 + 4] - __uint_as_float(c << 16);
      float l5 = p[s8 + 5] - __uint_as_float(c & 0xFFFF0000u);
      float l6 = p[s8 + 6] - __uint_as_float(d << 16);
      float l7 = p[s8 + 7] - __uint_as_float(d & 0xFFFF0000u);
      unsigned al = cvt_pk_bf16(l0, l1);
      unsigned bl = cvt_pk_bf16(l2, l3);
      unsigned cl = cvt_pk_bf16(l4, l5);
      unsigned dl = cvt_pk_bf16(l6, l7);
      plane_swap(a, c); plane_swap(bw, d);
      plane_swap(al, cl); plane_swap(bl, dl);
      union { unsigned w[4]; bf16x8 v; } PH, PL;
      PH.w[0] = a;  PH.w[1] = bw; PH.w[2] = c;  PH.w[3] = d;
      PL.w[0] = al; PL.w[1] = bl; PL.w[2] = cl; PL.w[3] = dl;
      pHf[s2] = PH.v; pLf[s2] = PL.v;
    }
    // PV: O^T += V^T @ P^T (3-term split), two independent 6-chains
    #pragma unroll
    for (int s2 = 0; s2 < 2; ++s2) {
      accO0 = __builtin_amdgcn_mfma_f32_32x32x16_bf16(vAH[0][s2], pHf[s2], accO0, 0, 0, 0);
      accO1 = __builtin_amdgcn_mfma_f32_32x32x16_bf16(vAH[1][s2], pHf[s2], accO1, 0, 0, 0);
      accO0 = __builtin_amdgcn_mfma_f32_32x32x16_bf16(vAH[0][s2], pLf[s2], accO0, 0, 0, 0);
      accO1 = __builtin_amdgcn_mfma_f32_32x32x16_bf16(vAH[1][s2], pLf[s2], accO1, 0, 0, 0);
      accO0 = __builtin_amdgcn_mfma_f32_32x32x16_bf16(vAL[0][s2], pHf[s2], accO0, 0, 0, 0);
      accO1 = __builtin_amdgcn_mfma_f32_32x32x16_bf16(vAL[1][s2], pHf[s2], accO1, 0, 0, 0);
    }
  }
  // ---- store partials (unnormalized). lane holds O[q][d=dblk*32+crow(r,LH)]
  if (LH == 0) {
    Mpart[slot * 128 + w * 32 + q] = m;
    Lpart[slot * 128 + w * 32 + q] = lsum;
  }
  float* Ob = Opart + (size_t)slot * 8192 + (w * 32 + q) * 64;
  #pragma unroll
  for (int g2 = 0; g2 < 4; ++g2) {
    float4 v0 = {accO0[g2 * 4 + 0], accO0[g2 * 4 + 1], accO0[g2 * 4 + 2], accO0[g2 * 4 + 3]};
    *(float4*)(Ob + 8 * g2 + 4 * LH) = v0;
    float4 v1 = {accO1[g2 * 4 + 0], accO1[g2 * 4 + 1], accO1[g2 * 4 + 2], accO1[g2 * 4 + 3]};
    *(float4*)(Ob + 32 + 8 * g2 + 4 * LH) = v1;
  }
}

// ---------------------------------------------------------------- merge partials (deterministic)
__global__ __launch_bounds__(256)
void fmerge2_kernel(const float* __restrict__ Opart, const float* __restrict__ Mpart,
                    const float* __restrict__ Lpart, float* __restrict__ o) {
  int qt = blockIdx.x, bh = blockIdx.y;
  int h = bh & 15, b = bh >> 4;
  int g = qt >> 2;
  int nc = g + 1;
  int off = 2 * g * (g + 1) + (qt & 3) * (g + 1);
  int slot0 = bh * 40 + off;
  int tid = threadIdx.x;
  int q = tid & 127, dh = tid >> 7;
  float mg = -3.402823466e38f;
  for (int c = 0; c < nc; ++c) mg = fmaxf(mg, Mpart[(slot0 + c) * 128 + q]);
  float lg = 0.0f;
  float4 acc[8] = {};
  for (int c = 0; c < nc; ++c) {
    float sc = __expf(Mpart[(slot0 + c) * 128 + q] - mg);
    lg += sc * Lpart[(slot0 + c) * 128 + q];
    const float4* op = (const float4*)(Opart + (size_t)(slot0 + c) * 8192 + q * 64 + dh * 32);
    #pragma unroll
    for (int i = 0; i < 8; ++i) {
      float4 v = op[i];
      acc[i].x += sc * v.x; acc[i].y += sc * v.y;
      acc[i].z += sc * v.z; acc[i].w += sc * v.w;
    }
  }
  float inv = 1.0f / lg;
  float* ob = o + ((size_t)(b * TT + qt * 128 + q)) * 1024 + h * 64 + dh * 32;
  #pragma unroll
  for (int i = 0; i < 8; ++i) {
    float4 v = {acc[i].x * inv, acc[i].y * inv, acc[i].z * inv, acc[i].w * inv};
    *(float4*)(ob + i * 4) = v;
  }
}

// ---------------------------------------------------------------- transpose + bf16 convert (+lo split)
template<bool LO>
__global__ void tconv_kernel(const float* __restrict__ in, ushort* __restrict__ oh,
                             ushort* __restrict__ ol, int K, int N) {
  __shared__ float t[32][33];
  int z = blockIdx.z;
  const float* ip = in + (size_t)z * K * N;
  ushort* ohp = oh + (size_t)z * K * N;
  ushort* olp = LO ? (ol + (size_t)z * K * N) : nullptr;
  int n0 = blockIdx.x * 32, k0 = blockIdx.y * 32;
  int tx = threadIdx.x, ty = threadIdx.y;   // (32,8)
  #pragma unroll
  for (int i = 0; i < 4; ++i)
    t[ty + 8 * i][tx] = ip[(size_t)(k0 + ty + 8 * i) * N + n0 + tx];
  __syncthreads();
  #pragma unroll
  for (int i = 0; i < 4; ++i) {
    float v = t[tx][ty + 8 * i];
    size_t off = (size_t)(n0 + ty + 8 * i) * K + k0 + tx;
    ushort hb = f2bf(v);
    ohp[off] = hb;
    if (LO) olp[off] = f2bf(v - bf2f(hb));
  }
}

// ---------------------------------------------------------------- rowwise hi/lo bf16 split
__global__ __launch_bounds__(256)
void split_kernel(const float* __restrict__ in, ushort* __restrict__ oh,
                  ushort* __restrict__ ol) {
  size_t i = ((size_t)blockIdx.x * 256 + threadIdx.x) * 4;
  float4 v = *(const float4*)(in + i);
  ushort h0 = f2bf(v.x), h1 = f2bf(v.y), h2 = f2bf(v.z), h3 = f2bf(v.w);
  ushort4 hh = {h0, h1, h2, h3};
  *(ushort4*)(oh + i) = hh;
  ushort4 ll = {f2bf(v.x - bf2f(h0)), f2bf(v.y - bf2f(h1)),
                f2bf(v.z - bf2f(h2)), f2bf(v.w - bf2f(h3))};
  *(ushort4*)(ol + i) = ll;
}

// ---------------------------------------------------------------- MFMA GEMM (unchanged)
#define LOAD_STEP(tt) do {                                                     \
    int seg = SPLIT3 ? ((tt) / kPer) : 0;                                      \
    int kk = (SPLIT3 ? ((tt) % kPer) : (tt)) << 6;                             \
    const ushort* Ause = (SPLIT3 && seg == 2) ? AlB : AhB;                     \
    const ushort* Buse = (SPLIT3 && seg == 1) ? BlB : BhB;                     \
    _Pragma("unroll")                                                          \
    for (int q = 0; q < 4; ++q) {                                              \
      int rr = r0 + 32 * q;                                                    \
      int clog = cph ^ (rr & 7);                                               \
      ra[q] = *(const bf16x8*)(Ause + (size_t)garow[q] * K + kk + clog * 8);   \
      rb[q] = *(const bf16x8*)(Buse + (size_t)(bn + rr) * K + kk + clog * 8);  \
    }                                                                          \
  } while (0)

template<int EPI, bool GATHER, bool SPLIT3>
__global__ __launch_bounds__(256, 2)
void mgemm(const ushort* __restrict__ Ah, const ushort* __restrict__ Al,
           const ushort* __restrict__ Bh, const ushort* __restrict__ Bl,
           void* __restrict__ Cv, const float* __restrict__ extra,
           const int* __restrict__ gatAll, int N, int K,
           long aEStride, long bEStride, long cEStride, int biasEStride) {
  __shared__ ushort As[128 * 64];
  __shared__ ushort Bs[128 * 64];
  int z = blockIdx.z;
  const ushort* AhB = Ah + (size_t)z * aEStride;
  const ushort* AlB = SPLIT3 ? (Al + (size_t)z * aEStride) : nullptr;
  const ushort* BhB = Bh + (size_t)z * bEStride;
  const ushort* BlB = SPLIT3 ? (Bl + (size_t)z * bEStride) : nullptr;
  const int* gat = GATHER ? (gatAll + z * 1024) : nullptr;
  int bm = blockIdx.y * 128, bn = blockIdx.x * 128;
  int tid = threadIdx.x;
  int r0 = tid >> 3, cph = tid & 7;
  int garow[4];
  #pragma unroll
  for (int q = 0; q < 4; ++q) {
    int rr = r0 + 32 * q;
    garow[q] = GATHER ? gat[bm + rr] : (bm + rr);
  }
  int kPer = K >> 6;
  int kSteps = (SPLIT3 ? 3 : 1) * kPer;
  int wid = tid >> 6, lane = tid & 63;
  int wm = wid >> 1, wn = wid & 1;
  int lr = lane & 15, lk = lane >> 4;
  f32x4 acc[4][4] = {};
  bf16x8 ra[4], rb[4];
  LOAD_STEP(0);
  for (int t = 0; t < kSteps; ++t) {
    __syncthreads();
    #pragma unroll
    for (int q = 0; q < 4; ++q) {
      int rr = r0 + 32 * q;
      *(bf16x8*)&As[rr * 64 + cph * 8] = ra[q];
      *(bf16x8*)&Bs[rr * 64 + cph * 8] = rb[q];
    }
    __syncthreads();
    if (t + 1 < kSteps) LOAD_STEP(t + 1);
    #pragma unroll
    for (int kh = 0; kh < 2; ++kh) {
      bf16x8 af[4], bfr[4];
      #pragma unroll
      for (int mf = 0; mf < 4; ++mf) {
        int row = wm * 64 + mf * 16 + lr;
        int ch = (kh * 4 + lk) ^ (row & 7);
        af[mf] = *(const bf16x8*)&As[row * 64 + ch * 8];
      }
      #pragma unroll
      for (int nf = 0; nf < 4; ++nf) {
        int row = wn * 64 + nf * 16 + lr;
        int ch = (kh * 4 + lk) ^ (row & 7);
        bfr[nf] = *(const bf16x8*)&Bs[row * 64 + ch * 8];
      }
      #pragma unroll
      for (int mf = 0; mf < 4; ++mf)
        #pragma unroll
        for (int nf = 0; nf < 4; ++nf)
          acc[mf][nf] = __builtin_amdgcn_mfma_f32_16x16x32_bf16(af[mf], bfr[nf], acc[mf][nf], 0, 0, 0);
    }
  }
  int crow = bm + wm * 64, ccol = bn + wn * 64;
  if constexpr (EPI <= 1) {
    float* C = (float*)Cv;
    #pragma unroll
    for (int mf = 0; mf < 4; ++mf)
      #pragma unroll
      for (int nf = 0; nf < 4; ++nf)
        #pragma unroll
        for (int r = 0; r < 4; ++r) {
          int row = crow + mf * 16 + lk * 4 + r;
          int col = ccol + nf * 16 + lr;
          float v = acc[mf][nf][r];
          if constexpr (EPI == 1) v += extra[(size_t)row * N + col];
          C[(size_t)row * N + col] = v;
        }
  } else {
    const float* bias = extra + (size_t)z * biasEStride;
    ushort* C = (ushort*)Cv + (size_t)z * cEStride;
    #pragma unroll
    for (int mf = 0; mf < 4; ++mf)
      #pragma unroll
      for (int nf = 0; nf < 4; ++nf)
        #pragma unroll
        for (int r = 0; r < 4; ++r) {
          int row = crow + mf * 16 + lk * 4 + r;
          int col = ccol + nf * 16 + lr;
          float v = acc[mf][nf][r] + bias[col];
          if constexpr (EPI == 2)
            v = 0.5f * v * (1.0f + erff(v * 0.70710678118654752f));
          C[(size_t)row * N + col] = f2bf(v);
        }
  }
}

// ---------------------------------------------------------------- gate: softmax + stable top-2
__global__ __launch_bounds__(256)
void gate_kernel(const float* __restrict__ ffin, const float* __restrict__ Wg,
                 int* __restrict__ te, float* __restrict__ tv, int* __restrict__ inv) {
  int token = blockIdx.x, tid = threadIdx.x;
  float acc[8] = {};
  const float* xr = ffin + (size_t)token * 1024;
  for (int i = tid; i < 1024; i += 256) {
    float xv = xr[i];
    const float4* wr = (const float4*)&Wg[i * 8];
    float4 w0 = wr[0], w1 = wr[1];
    acc[0] += xv * w0.x; acc[1] += xv * w0.y; acc[2] += xv * w0.z; acc[3] += xv * w0.w;
    acc[4] += xv * w1.x; acc[5] += xv * w1.y; acc[6] += xv * w1.z; acc[7] += xv * w1.w;
  }
  #pragma unroll
  for (int off = 1; off < 64; off <<= 1)
    #pragma unroll
    for (int q = 0; q < 8; ++q) acc[q] += __shfl_xor(acc[q], off);
  __shared__ float red[4][8];
  if ((tid & 63) == 0)
    #pragma unroll
    for (int q = 0; q < 8; ++q) red[tid >> 6][q] = acc[q];
  __syncthreads();
  if (tid == 0) {
    float g[8];
    #pragma unroll
    for (int q = 0; q < 8; ++q) g[q] = red[0][q] + red[1][q] + red[2][q] + red[3][q];
    float mx = g[0];
    #pragma unroll
    for (int q = 1; q < 8; ++q) mx = fmaxf(mx, g[q]);
    float sum = 0.0f;
    #pragma unroll
    for (int q = 0; q < 8; ++q) { g[q] = expf(g[q] - mx); sum += g[q]; }
    float inv_s = 1.0f / sum;
    #pragma unroll
    for (int q = 0; q < 8; ++q) g[q] *= inv_s;
    int e1 = 0; float v1 = g[0];
    for (int q = 1; q < 8; ++q) if (g[q] > v1) { v1 = g[q]; e1 = q; }
    int e2 = -1; float v2 = -1.0f;
    for (int q = 0; q < 8; ++q) { if (q == e1) continue; if (g[q] > v2) { v2 = g[q]; e2 = q; } }
    te[token * 2] = e1; te[token * 2 + 1] = e2;
    tv[token * 2] = v1; tv[token * 2 + 1] = v2;
    inv[token * 2] = -1; inv[token * 2 + 1] = -1;
  }
}

// ---------------------------------------------------------------- per-expert capacity select v2
__global__ __launch_bounds__(1024)
void route_sort_kernel(const int* __restrict__ te, const float* __restrict__ tv,
                       int* __restrict__ etok, float* __restrict__ ew,
                       int* __restrict__ inv) {
  __shared__ unsigned long long sk[4096];
  __shared__ int wcnt[16];
  __shared__ int base;
  int e = blockIdx.x, tid = threadIdx.x;
  int lane = tid & 63, wv = tid >> 6;
  if (tid == 0) base = 0;
  __syncthreads();
  for (int c = 0; c < 8; ++c) {
    int s = c * 1024 + tid;
    bool sel = (te[s] == e);
    unsigned long long ball = __ballot(sel);
    int pre = __popcll(ball & ((1ull << lane) - 1ull));
    if (lane == 0) wcnt[wv] = __popcll(ball);
    __syncthreads();
    int woff = 0, tot = 0;
    #pragma unroll
    for (int i = 0; i < 16; ++i) {
      int cc = wcnt[i];
      if (i < wv) woff += cc;
      tot += cc;
    }
    if (sel) {
      unsigned vb = __float_as_uint(tv[s]);
      sk[base + woff + pre] =
          ((unsigned long long)vb << 32) | (unsigned)(0xFFFFFFFFu - (unsigned)s);
    }
    __syncthreads();
    if (tid == 0) base += tot;
    __syncthreads();
  }
  int n = base;
  if (n > 1024) {
    int P = (n <= 2048) ? 2048 : 4096;
    for (int i = n + tid; i < P; i += 1024) sk[i] = 0ull;
    __syncthreads();
    for (int k = 2; k <= P; k <<= 1)
      for (int j = k >> 1; j > 0; j >>= 1) {
        for (int t = tid; t < (P >> 1); t += 1024) {
          int i = ((t & ~(j - 1)) << 1) | (t & (j - 1));
          int p = i | j;
          unsigned long long a = sk[i], bq = sk[p];
          bool desc = ((i & k) == 0);
          if (desc ? (a < bq) : (a > bq)) { sk[i] = bq; sk[p] = a; }
        }
        __syncthreads();
      }
  }
  int cap = n < 1024 ? n : 1024;
  if (tid < cap) {
    unsigned long long key = sk[tid];
    unsigned slot = 0xFFFFFFFFu - (unsigned)(key & 0xFFFFFFFFull);
    etok[e * 1024 + tid] = (int)(slot >> 1);
    ew[e * 1024 + tid] = __uint_as_float((unsigned)(key >> 32));
    inv[slot] = e * 1024 + tid;
  } else {
    etok[e * 1024 + tid] = 0;
    ew[e * 1024 + tid] = 0.0f;
  }
}

// ---------------------------------------------------------------- final combine (deterministic)
__global__ __launch_bounds__(256)
void combine_kernel(const float* __restrict__ xres, const ushort* __restrict__ eo,
                    const int* __restrict__ inv, const float* __restrict__ ew,
                    float* __restrict__ outx, float* __restrict__ aux) {
  int token = blockIdx.x;
  int d = threadIdx.x * 4;
  float4 acc = *(const float4*)&xres[(size_t)token * 1024 + d];
  #pragma unroll
  for (int j = 0; j < 2; ++j) {
    int p = inv[token * 2 + j];
    if (p >= 0) {
      float w = ew[p];
      const ushort* ep = eo + (size_t)p * 1024 + d;
      acc.x += w * bf2f(ep[0]); acc.y += w * bf2f(ep[1]);
      acc.z += w * bf2f(ep[2]); acc.w += w * bf2f(ep[3]);
    }
  }
  *(float4*)&outx[(size_t)token * 1024 + d] = acc;
  if (token == 0 && threadIdx.x == 0) aux[0] = 0.0f;
}

// ================================================================ launch
extern "C" void kernel_launch(void* const* d_in, const int* in_sizes, int n_in,
                              void* d_out, int out_size, void* d_ws, size_t ws_size,
                              hipStream_t stream) {
  const float* x     = (const float*)d_in[0];
  const float* ln1g  = (const float*)d_in[1];
  const float* ln1b  = (const float*)d_in[2];
  const float* ln2g  = (const float*)d_in[3];
  const float* ln2b  = (const float*)d_in[4];
  const float* Wqkv  = (const float*)d_in[5];
  const float* Wproj = (const float*)d_in[6];
  const float* Wg    = (const float*)d_in[7];
  const float* W1    = (const float*)d_in[8];
  const float* b1    = (const float*)d_in[9];
  const float* W2    = (const float*)d_in[10];
  const float* b2    = (const float*)d_in[11];

  float* out_x   = (float*)d_out;
  float* out_aux = out_x + 4194304;
  float* out_k   = out_aux + 1;
  float* out_v   = out_k + 4194304;

  float* ws   = (float*)d_ws;
  float* A    = ws;                          // x_norm -> x_res
  float* qkvb = ws + 4194304;                // fp32 qkv (aliased by h later)
  float* o    = ws + 16777216;               // attn out -> ff_in
  float* st   = ws + 20971520;
  float* ct   = ws + 21037056;
  int*   te   = (int*)(ws + 21102592);
  float* tv   = ws + 21110784;
  int*   etok = (int*)(ws + 21118976);
  float* ew   = ws + 21127168;
  int*   inv  = (int*)(ws + 21135360);
  ushort* bfAh = (ushort*)(ws + 21143552);   // [4096][1024] bf16
  ushort* bfAl = (ushort*)(ws + 23240704);
  ushort* BqH  = (ushort*)(ws + 25337856);   // WqkvT hi [3072][1024]
  ushort* BqL  = (ushort*)(ws + 26910720);
  ushort* BpH  = (ushort*)(ws + 28483584);   // WprojT hi [1024][1024]
  ushort* BpL  = (ushort*)(ws + 29007872);
  ushort* W1t  = (ushort*)(ws + 29532160);   // [8][4096][1024] (written AFTER fmerge)
  ushort* W2t  = (ushort*)(ws + 46309376);   // [8][1024][4096]
  ushort* eo   = (ushort*)(ws + 63086592);   // [8192][1024] bf16
  ushort* hbuf = (ushort*)(ws + 4194304);    // [8][1024][4096] bf16, aliases qkvb+o
  // flash operand buffers (aliased into dead regions during attention):
  ushort* Kh_  = bfAh;                       // [2][16][2048][64]
  ushort* Kl_  = bfAl;
  ushort* Vth_ = eo;                         // [2][16][64][2048]
  ushort* Vtl_ = eo + 4194304;
  // split-KV partials alias the (not-yet-written) W1t region:
  float* Opart = ws + 29532160;              // [1280][128][64]
  float* Mpart = ws + 40017920;              // [1280][128]
  float* Lpart = ws + 40181760;              // [1280][128]

  // weight prep needed before flash (W1/W2 transposes moved after fmerge)
  tconv_kernel<true ><<<dim3(96, 32, 1),  dim3(32, 8), 0, stream>>>(Wqkv,  BqH, BqL, 1024, 3072);
  tconv_kernel<true ><<<dim3(32, 32, 1),  dim3(32, 8), 0, stream>>>(Wproj, BpH, BpL, 1024, 1024);
  sincos_kernel<<<TT, 32, 0, stream>>>(st, ct);

  // LN1 + split
  ln_kernel<<<NTOK, 256, 0, stream>>>(x, ln1g, ln1b, A);
  split_kernel<<<4096, 256, 0, stream>>>(A, bfAh, bfAl);
  // QKV (split-bf16, K' = 3*1024)
  mgemm<0, false, true><<<dim3(24, 32, 1), 256, 0, stream>>>(
      bfAh, bfAl, BqH, BqL, qkvb, nullptr, nullptr, 3072, 1024, 0, 0, 0, 0);
  // RoPE + k/v outputs + Kh/Kl prep (bfAh/bfAl dead now)
  rope_kernel<<<NTOK, 256, 0, stream>>>(qkvb, st, ct, out_k, out_v, Kh_, Kl_);
  vtprep_kernel<<<dim3(32, 16, 2), 256, 0, stream>>>(out_v, Vth_, Vtl_);
  // split-KV flash + merge
  flash6_kernel<<<1280, 256, 0, stream>>>(qkvb, Kh_, Kl_, Vth_, Vtl_, Opart, Mpart, Lpart);
  fmerge2_kernel<<<dim3(16, 32), 256, 0, stream>>>(Opart, Mpart, Lpart, o);
  // proj + residual (split-bf16; clobbers Kh/Kl — dead)
  split_kernel<<<4096, 256, 0, stream>>>(o, bfAh, bfAl);
  mgemm<1, false, true><<<dim3(8, 32, 1), 256, 0, stream>>>(
      bfAh, bfAl, BpH, BpL, A, x, nullptr, 1024, 1024, 0, 0, 0, 0);
  // expert weight prep (W1t region free again after fmerge)
  tconv_kernel<false><<<dim3(128, 32, 8), dim3(32, 8), 0, stream>>>(W1, W1t, nullptr, 1024, 4096);
  tconv_kernel<false><<<dim3(32, 128, 8), dim3(32, 8), 0, stream>>>(W2, W2t, nullptr, 4096, 1024);
  // LN2 -> ff_in (in o buffer), gate, route
  ln_kernel<<<NTOK, 256, 0, stream>>>(A, ln2g, ln2b, o);
  gate_kernel<<<NTOK, 256, 0, stream>>>(o, Wg, te, tv, inv);
  split_kernel<<<4096, 256, 0, stream>>>(o, bfAh, bfAl);   // ffin bf16 (hi used)
  route_sort_kernel<<<8, 1024, 0, stream>>>(te, tv, etok, ew, inv);
  // experts: up (gather + gelu -> bf16 h), down (-> bf16 eo; clobbers Vth/Vtl — dead)
  mgemm<2, true, false><<<dim3(32, 8, 8), 256, 0, stream>>>(
      bfAh, nullptr, W1t, nullptr, hbuf, b1, etok, 4096, 1024,
      0, 4096L * 1024, 1024L * 4096, 4096);
  mgemm<3, false, false><<<dim3(8, 8, 8), 256, 0, stream>>>(
      hbuf, nullptr, W2t, nullptr, eo, b2, nullptr, 1024, 4096,
      1024L * 4096, 1024L * 4096, 1024L * 1024, 1024);
  combine_kernel<<<NTOK, 256, 0, stream>>>(A, eo, inv, ew, out_x, out_aux);
}